// Round 15
// baseline (1988.492 us; speedup 1.0000x reference)
//
#include <hip/hip_runtime.h>
#include <math.h>

// GPT fwd: B=4, S=1024, L=8, H=16, E=1024, D=64, HID=4096, V=1000
// Workspace requirement: ~120 MB (see offsets below).

typedef unsigned short u16;
typedef unsigned int u32;
typedef __attribute__((ext_vector_type(4))) float f32x4;
typedef __attribute__((ext_vector_type(16))) float f32x16;
typedef __attribute__((ext_vector_type(8))) __bf16 bf16x8;
typedef __attribute__((ext_vector_type(8))) u16 u16x8;
typedef __attribute__((ext_vector_type(4))) u16 u16x4;

#define E 1024
#define HID 4096
#define NH 16
#define HD 64
#define SEQ 1024
#define NB 4
#define NL 8
#define MTOK 4096
#define VOC 1000

#define VMCNT(n) asm volatile("s_waitcnt vmcnt(" #n ")" ::: "memory")

__device__ __forceinline__ u16 f2bf(float f){
  u32 u = __float_as_uint(f);
  u32 r = (u + 0x7fffu + ((u >> 16) & 1u)) >> 16;
  return (u16)r;
}
__device__ __forceinline__ float bf2f(u16 b){
  return __uint_as_float((u32)b << 16);
}
__device__ __forceinline__ bf16x8 ld_bf8(const u16* p){
  return *reinterpret_cast<const bf16x8*>(p);
}
__device__ __forceinline__ bf16x8 as_bf(u16x8 v){
  return __builtin_bit_cast(bf16x8, v);
}

// async global->LDS, 16B per lane; LDS dest = wave-uniform base + lane*16 (HW)
__device__ __forceinline__ void gload16(const void* g, void* l){
  __builtin_amdgcn_global_load_lds(
      (const __attribute__((address_space(1))) void*)g,
      (__attribute__((address_space(3))) void*)l, 16, 0, 0);
}

// ---------------- embed: x = wte[idx] + wpe[s] ----------------
__global__ __launch_bounds__(256) void embed_kernel(
    const int* __restrict__ idx, const float* __restrict__ wte,
    const float* __restrict__ wpe, float* __restrict__ x)
{
  int tok = blockIdx.x, tid = threadIdx.x;
  int id = idx[tok];
  int s = tok & (SEQ - 1);
  f32x4 a = *reinterpret_cast<const f32x4*>(&wte[(size_t)id * E + tid * 4]);
  f32x4 p = *reinterpret_cast<const f32x4*>(&wpe[(size_t)s * E + tid * 4]);
  f32x4 r = a + p;
  *reinterpret_cast<f32x4*>(&x[(size_t)tok * E + tid * 4]) = r;
}

// ---------------- layernorm: h = LN(x)*w + b (bf16 out) ----------------
__global__ __launch_bounds__(256) void ln_kernel(
    const float* __restrict__ x, const float* __restrict__ w,
    const float* __restrict__ b, u16* __restrict__ h)
{
  int row = blockIdx.x, tid = threadIdx.x;
  const float* xr = x + (size_t)row * E;
  f32x4 v = *reinterpret_cast<const f32x4*>(xr + tid * 4);
  float s = v[0] + v[1] + v[2] + v[3];
  float q = v[0]*v[0] + v[1]*v[1] + v[2]*v[2] + v[3]*v[3];
  #pragma unroll
  for (int mm = 1; mm < 64; mm <<= 1){
    s += __shfl_xor(s, mm);
    q += __shfl_xor(q, mm);
  }
  __shared__ float red[8];
  int wv = tid >> 6;
  if ((tid & 63) == 0){ red[wv] = s; red[4 + wv] = q; }
  __syncthreads();
  s = red[0] + red[1] + red[2] + red[3];
  q = red[4] + red[5] + red[6] + red[7];
  float mean = s * (1.0f / E);
  float var = q * (1.0f / E) - mean * mean;
  float rstd = rsqrtf(var + 1e-5f);
  f32x4 wv4 = *reinterpret_cast<const f32x4*>(w + tid * 4);
  f32x4 bv4 = *reinterpret_cast<const f32x4*>(b + tid * 4);
  u16 o0 = f2bf((v[0] - mean) * rstd * wv4[0] + bv4[0]);
  u16 o1 = f2bf((v[1] - mean) * rstd * wv4[1] + bv4[1]);
  u16 o2 = f2bf((v[2] - mean) * rstd * wv4[2] + bv4[2]);
  u16 o3 = f2bf((v[3] - mean) * rstd * wv4[3] + bv4[3]);
  u16* hp = &h[(size_t)row * E + tid * 4];
  hp[0] = o0; hp[1] = o1; hp[2] = o2; hp[3] = o3;
}

// ------- merged per-layer weight convert+transpose (all Nsrc % 64 == 0) -------
__global__ __launch_bounds__(256) void wconv4_kernel(
    const float* __restrict__ qw, const float* __restrict__ ow,
    const float* __restrict__ f1, const float* __restrict__ f2,
    u16* __restrict__ dq, u16* __restrict__ d_unused, u16* __restrict__ d1,
    u16* __restrict__ d2, u16* __restrict__ dw_out)
{
  const int bid = blockIdx.x, tid = threadIdx.x;
  const float* W; u16* Wt; int K, Nsrc, nx, base;
  if (bid < 768)      { W = qw; Wt = dq;     K = 1024; Nsrc = 3072; nx = 48; base = 0; }
  else if (bid < 1024){ W = ow; Wt = dw_out; K = 1024; Nsrc = 1024; nx = 16; base = 768; }
  else if (bid < 2048){ W = f1; Wt = d1;     K = 1024; Nsrc = 4096; nx = 64; base = 1024; }
  else                { W = f2; Wt = d2;     K = 4096; Nsrc = 1024; nx = 16; base = 2048; }
  const int t = bid - base;
  const int n0 = (t % nx) * 64, k0 = (t / nx) * 64;

  __shared__ float T[64][65];
  const int c = (tid & 15) * 4, rbase = tid >> 4;
  #pragma unroll
  for (int p = 0; p < 4; p++){
    int r = rbase + p * 16;
    f32x4 v = *reinterpret_cast<const f32x4*>(&W[(size_t)(k0 + r) * Nsrc + n0 + c]);
    T[r][c] = v[0]; T[r][c+1] = v[1]; T[r][c+2] = v[2]; T[r][c+3] = v[3];
  }
  __syncthreads();
  const int nr = tid >> 2, ks = (tid & 3) * 16;
  u16x8 o0, o1;
  #pragma unroll
  for (int i = 0; i < 8; i++){
    o0[i] = f2bf(T[ks + i][nr]);
    o1[i] = f2bf(T[ks + 8 + i][nr]);
  }
  u16* dst = &Wt[(size_t)(n0 + nr) * K + k0 + ks];
  *reinterpret_cast<u16x8*>(dst) = o0;
  *reinterpret_cast<u16x8*>(dst + 8) = o1;
}

// ------- single weight convert+transpose (head: Nsrc=1000 padded to 1024) -----
__global__ __launch_bounds__(256) void wconv_kernel(
    const float* __restrict__ W, u16* __restrict__ Wt,
    int K, int Nsrc, int N)
{
  __shared__ float T[64][65];
  const int tid = threadIdx.x;
  const int n0 = blockIdx.x * 64, k0 = blockIdx.y * 64;
  const int c = (tid & 15) * 4, rbase = tid >> 4;
  #pragma unroll
  for (int p = 0; p < 4; p++){
    int r = rbase + p * 16;
    #pragma unroll
    for (int j = 0; j < 4; j++){
      int n = n0 + c + j;
      T[r][c + j] = (n < Nsrc) ? W[(size_t)(k0 + r) * Nsrc + n] : 0.0f;
    }
  }
  __syncthreads();
  const int nr = tid >> 2, ks = (tid & 3) * 16;
  u16x8 o0, o1;
  #pragma unroll
  for (int i = 0; i < 8; i++){
    o0[i] = f2bf(T[ks + i][nr]);
    o1[i] = f2bf(T[ks + 8 + i][nr]);
  }
  u16* dst = &Wt[(size_t)(n0 + nr) * K + k0 + ks];
  *reinterpret_cast<u16x8*>(dst) = o0;
  *reinterpret_cast<u16x8*>(dst + 8) = o1;
}

// ---------------- GEMM: C = A(bf16)[M,K] @ Wt(bf16)[N,K]^T + bias ----------------
// 32x32x16 MFMA. NS=4 ring, BK=32, phase split (r13):
//   [ds_read frags(c) -> VMCNT(4) -> s_barrier -> setprio+MFMA(c) -> STAGE(c+3)]
// FM/FN in units of 32. A/B frag: row=lane&31, k=(lane>>5)*8+j (4 VGPR).
// C/D: col=lane&31, row=(reg&3)+8*(reg>>2)+4*(lane>>5) [m74/m101 verified].
// T1 XCD swizzle, T2 16B-slot XOR swizzle (slot ^ ((row>>2)&3), both sides), T5.
enum { EPI_BF16 = 0, EPI_GELU = 1, EPI_RESID = 2, EPI_OUT = 3 };

template<int EPI, int NW, int NWX, int FM, int FN, int MINW>
__global__ __launch_bounds__(NW * 64, MINW) void gemm2_kernel(
    const u16* __restrict__ A, const u16* __restrict__ Wt,
    const float* __restrict__ bias, void* __restrict__ outp,
    float* __restrict__ xres, int M, int N, int K)
{
  constexpr int BM = FM * 32 * (NW / NWX);
  constexpr int BN = FN * 32 * NWX;
  constexpr int SLOT = (BM + BN) * 32;       // u16 per slot (A | B), BK=32
  constexpr int GROUPS = (BM + BN) / 16;
  constexpr int RPW = GROUPS / NW;
  static_assert(RPW == 4, "staging assumes 4 gloads/wave/chunk");
  constexpr int NS = 4;
  extern __shared__ u16 lds[];               // NS * SLOT * 2 bytes

  const int tid = threadIdx.x;
  const int lane = tid & 63, w = tid >> 6;
  const int l31 = lane & 31, hi = lane >> 5;
  const int wr = w / NWX, wc = w % NWX;
  const int wrbase = wr * FM * 32, wcbase = wc * FN * 32;
  const int rs4 = (lane >> 2) & 3;           // read-swizzle component ((row>>2)&3)

  // T1: bijective XCD swizzle (all grids have nwg % 8 == 0)
  const int nwgx = gridDim.x;
  const int bid = blockIdx.y * nwgx + blockIdx.x;
  const int cpx = (nwgx * gridDim.y) >> 3;
  const int swz = (bid & 7) * cpx + (bid >> 3);
  const int bm = (swz / nwgx) * BM, bn = (swz % nwgx) * BN;

  const u16* Abase = A + (size_t)bm * K;
  const u16* Bbase = Wt + (size_t)bn * K;

  f32x16 acc[FM][FN];
  #pragma unroll
  for (int i = 0; i < FM; i++)
    #pragma unroll
    for (int j = 0; j < FN; j++)
      #pragma unroll
      for (int r = 0; r < 16; r++)
        acc[i][j][r] = 0.f;

  // stage chunk cc into slot s: 4 gload16/wave over combined A|B row space.
  const int lr = lane >> 2, ps = lane & 3;
  const int ss = ps ^ ((lane >> 4) & 3);     // source pre-swizzle
  auto STAGE = [&](int s, int cc){
    const int k0 = cc * 32;
    u16* As = lds + s * SLOT;
    u16* Bs = As + BM * 32;
    #pragma unroll
    for (int j = 0; j < 4; j++){
      int base = (w * 4 + j) * 16;
      if (base < BM){
        gload16(&Abase[(size_t)(base + lr) * K + k0 + ss * 8], As + base * 32);
      } else {
        int rb = base - BM;
        gload16(&Bbase[(size_t)(rb + lr) * K + k0 + ss * 8], Bs + rb * 32);
      }
    }
  };

  const int nt = K >> 5;                     // >= 32 for all our shapes
  STAGE(0, 0); STAGE(1, 1); STAGE(2, 2);
  VMCNT(4);                                  // chunks 0,1 landed (chunk 2 in flight)
  __builtin_amdgcn_sched_barrier(0);
  __builtin_amdgcn_s_barrier();
  __builtin_amdgcn_sched_barrier(0);

  int sl = 0;
  for (int c = 0; c < nt; c++){
    // ---- ds_read frags of chunk c (both k-halves) ----
    const u16* As = lds + sl * SLOT;
    const u16* Bs = As + BM * 32;
    bf16x8 af[2][FM], bf[2][FN];
    #pragma unroll
    for (int ks = 0; ks < 2; ks++){
      const int sw = ((ks * 2 + hi) ^ rs4) * 8;
      #pragma unroll
      for (int mf = 0; mf < FM; mf++)
        af[ks][mf] = ld_bf8(&As[(wrbase + mf * 32 + l31) * 32 + sw]);
      #pragma unroll
      for (int nf = 0; nf < FN; nf++)
        bf[ks][nf] = ld_bf8(&Bs[(wcbase + nf * 32 + l31) * 32 + sw]);
    }
    __builtin_amdgcn_sched_barrier(0);
    if (c + 2 <= nt - 1) { VMCNT(4); } else { VMCNT(0); }
    __builtin_amdgcn_sched_barrier(0);
    __builtin_amdgcn_s_barrier();            // chunk c+1 visible; reads of c issued
    __builtin_amdgcn_sched_barrier(0);
    // ---- MFMA ----
    __builtin_amdgcn_s_setprio(1);
    #pragma unroll
    for (int ks = 0; ks < 2; ks++)
      #pragma unroll
      for (int mf = 0; mf < FM; mf++)
        #pragma unroll
        for (int nf = 0; nf < FN; nf++)
          acc[mf][nf] = __builtin_amdgcn_mfma_f32_32x32x16_bf16(
              af[ks][mf], bf[ks][nf], acc[mf][nf], 0, 0, 0);
    __builtin_amdgcn_s_setprio(0);
    // ---- prefetch chunk c+3 into slot (c-1)%4 (dead once waves passed barrier(c)) ----
    if (c + 3 < nt){
      int s2 = sl + 3; if (s2 >= NS) s2 -= NS;
      STAGE(s2, c + 3);
    }
    sl++; if (sl >= NS) sl -= NS;
  }

  // epilogue (C/D: col = lane&31, row = (reg&3) + 8*(reg>>2) + 4*hi)
  #pragma unroll
  for (int mf = 0; mf < FM; mf++){
    #pragma unroll
    for (int nf = 0; nf < FN; nf++){
      int col = bn + wcbase + nf * 32 + l31;
      float bv = bias[col];
      #pragma unroll
      for (int reg = 0; reg < 16; reg++){
        int row = bm + wrbase + mf * 32 + (reg & 3) + 8 * (reg >> 2) + 4 * hi;
        float v = acc[mf][nf][reg] + bv;
        if constexpr (EPI == EPI_BF16){
          ((u16*)outp)[(size_t)row * N + col] = f2bf(v);
        } else if constexpr (EPI == EPI_GELU){
          ((u16*)outp)[(size_t)row * N + col] =
              f2bf(0.5f * v * (1.0f + erff(v * 0.70710678118654752f)));
        } else if constexpr (EPI == EPI_RESID){
          xres[(size_t)row * N + col] += v;
        } else {
          if (col < VOC)
            ((float*)outp)[(size_t)row * VOC + col] = v;
        }
      }
    }
  }
}

// ---------------- flash attention (causal), paired 64-row q-blocks ----------------
__global__ __launch_bounds__(256) void attn_kernel(
    const u16* __restrict__ qkv, u16* __restrict__ y)
{
  __shared__ u16 Kl[64 * 64];       // [key][dslot swizzled], 8KB
  __shared__ u16 Vt[64 * 72];       // [d][c'], stride 72, 9KB
  __shared__ u16 Pl[4 * 16 * 72];   // per-wave [q][c'], 9KB
  const int pr = blockIdx.x, hh = blockIdx.y, b = blockIdx.z;
  const int tid = threadIdx.x;
  const int lane = tid & 63, w = tid >> 6;
  const int l15 = lane & 15, g = lane >> 4;
  const size_t tokbase = (size_t)b * SEQ;
  const int qstart[2] = { pr * 64, (15 - pr) * 64 };

  int qbase[2], dt[2];
  u16x8 q0[2], q1[2];
  f32x4 o[2][4];
  float m[2][4], llp[2][4];
  #pragma unroll
  for (int st = 0; st < 2; st++){
    qbase[st] = qstart[st] + w * 16;
    dt[st] = qbase[st] >> 6;
    const u16* qp = &qkv[(tokbase + qbase[st] + l15) * (3 * E) + hh * HD];
    u16x8 ra = *reinterpret_cast<const u16x8*>(&qp[g * 8]);
    u16x8 rb = *reinterpret_cast<const u16x8*>(&qp[32 + g * 8]);
    #pragma unroll
    for (int j = 0; j < 8; j++){
      q0[st][j] = f2bf(bf2f(ra[j]) * 0.125f);
      q1[st][j] = f2bf(bf2f(rb[j]) * 0.125f);
    }
    #pragma unroll
    for (int dc = 0; dc < 4; dc++) o[st][dc] = f32x4{0.f, 0.f, 0.f, 0.f};
    #pragma unroll
    for (int r = 0; r < 4; r++){ m[st][r] = -1e30f; llp[st][r] = 0.f; }
  }

  u16* Pw = &Pl[w * 16 * 72];
  const int T = 16 - pr;

  for (int t = 0; t < T; t++){
    const int k0 = t * 64;
    __syncthreads();
    #pragma unroll
    for (int j = 0; j < 2; j++){
      int row = w * 16 + j * 8 + (lane >> 3);
      int sl = lane & 7;
      const u16* src = &qkv[(tokbase + k0 + row) * (3 * E) + E + hh * HD
                            + ((sl ^ (row & 7)) * 8)];
      gload16(src, &Kl[w * 1024 + j * 512]);
    }
    {
      int d0 = (tid & 15) * 4;
      int s  = tid >> 4;
      #pragma unroll
      for (int mh = 0; mh < 2; mh++){
        int kA = s + 32 * mh;
        const u16* vpA = &qkv[(tokbase + k0 + kA) * (3 * E) + 2 * E + hh * HD + d0];
        const u16* vpB = vpA + 16 * (3 * E);
        u16x4 va = *reinterpret_cast<const u16x4*>(vpA);
        u16x4 vb = *reinterpret_cast<const u16x4*>(vpB);
        #pragma unroll
        for (int i = 0; i < 4; i++)
          *reinterpret_cast<u32*>(&Vt[(d0 + i) * 72 + 4 * s + 2 * mh]) =
              (u32)va[i] | ((u32)vb[i] << 16);
      }
    }
    __syncthreads();

    #pragma unroll
    for (int st = 0; st < 2; st++){
      if (t > dt[st]) continue;
      const bool diag = (t == dt[st]);
      f32x4 s[4];
      #pragma unroll
      for (int kg = 0; kg < 4; kg++){
        int key = kg * 16 + l15;
        const u16* kb = &Kl[key * 64];
        bf16x8 k0f = ld_bf8(&kb[(g ^ (key & 7)) * 8]);
        bf16x8 k1f = ld_bf8(&kb[((4 + g) ^ (key & 7)) * 8]);
        f32x4 z = f32x4{0.f, 0.f, 0.f, 0.f};
        z = __builtin_amdgcn_mfma_f32_16x16x32_bf16(as_bf(q0[st]), k0f, z, 0, 0, 0);
        z = __builtin_amdgcn_mfma_f32_16x16x32_bf16(as_bf(q1[st]), k1f, z, 0, 0, 0);
        s[kg] = z;
      }
      if (diag){
        #pragma unroll
        for (int kg = 0; kg < 4; kg++){
          int key = k0 + kg * 16 + l15;
          #pragma unroll
          for (int r = 0; r < 4; r++){
            int q = qbase[st] + g * 4 + r;
            s[kg][r] = (key <= q) ? s[kg][r] : -1e9f;
          }
        }
      }
      float lmax[4];
      bool need = false;
      #pragma unroll
      for (int r = 0; r < 4; r++){
        lmax[r] = fmaxf(fmaxf(s[0][r], s[1][r]), fmaxf(s[2][r], s[3][r]));
        need = need || (lmax[r] > m[st][r] + 8.0f);
      }
      if (__any(need)){
        #pragma unroll
        for (int r = 0; r < 4; r++){
          float x = lmax[r];
          x = fmaxf(x, __shfl_xor(x, 1));
          x = fmaxf(x, __shfl_xor(x, 2));
          x = fmaxf(x, __shfl_xor(x, 4));
          x = fmaxf(x, __shfl_xor(x, 8));
          float mn = fmaxf(m[st][r], x);
          float al = __expf(m[st][r] - mn);
          m[st][r] = mn;
          llp[st][r] *= al;
          #pragma unroll
          for (int dc = 0; dc < 4; dc++) o[st][dc][r] *= al;
        }
      }
      #pragma unroll
      for (int r = 0; r < 4; r++){
        float p0 = __expf(s[0][r] - m[st][r]);
        float p1 = __expf(s[1][r] - m[st][r]);
        float p2 = __expf(s[2][r] - m[st][r]);
        float p3 = __expf(s[3][r] - m[st][r]);
        llp[st][r] += (p0 + p1) + (p2 + p3);
        u16x4 pp = { f2bf(p0), f2bf(p1), f2bf(p2), f2bf(p3) };
        *reinterpret_cast<u16x4*>(&Pw[(g * 4 + r) * 72 + 4 * l15]) = pp;
      }
      bf16x8 pa0 = ld_bf8(&Pw[l15 * 72 + g * 8]);
      bf16x8 pa1 = ld_bf8(&Pw[l15 * 72 + 32 + g * 8]);
      #pragma unroll
      for (int dc = 0; dc < 4; dc++){
        bf16x8 v0 = ld_bf8(&Vt[(dc * 16 + l15) * 72 + g * 8]);
        bf16x8 v1 = ld_bf8(&Vt[(dc * 16 + l15) * 72 + 32 + g * 8]);
        o[st][dc] = __builtin_amdgcn_mfma_f32_16x16x32_bf16(pa0, v0, o[st][dc], 0, 0, 0);
        o[st][dc] = __builtin_amdgcn_mfma_f32_16x16x32_bf16(pa1, v1, o[st][dc], 0, 0, 0);
      }
    }
  }

  #pragma unroll
  for (int st = 0; st < 2; st++){
    #pragma unroll
    for (int r = 0; r < 4; r++){
      float rs = llp[st][r];
      rs += __shfl_xor(rs, 1);
      rs += __shfl_xor(rs, 2);
      rs += __shfl_xor(rs, 4);
      rs += __shfl_xor(rs, 8);
      float inv = 1.0f / rs;
      int row = qbase[st] + g * 4 + r;
      #pragma unroll
      for (int dc = 0; dc < 4; dc++){
        int col = hh * HD + dc * 16 + l15;
        y[(tokbase + row) * E + col] = f2bf(o[st][dc][r] * inv);
      }
    }
  }
}

// ---------------- head bias pad [1000] -> [1024] f32 ----------------
__global__ __launch_bounds__(256) void biaspad_kernel(
    const float* __restrict__ hb, float* __restrict__ bpad)
{
  int i = blockIdx.x * 256 + threadIdx.x;
  if (i < 1024) bpad[i] = (i < VOC) ? hb[i] : 0.0f;
}

// ---------------- launch ----------------
extern "C" void kernel_launch(void* const* d_in, const int* in_sizes, int n_in,
                              void* d_out, int out_size, void* d_ws, size_t ws_size,
                              hipStream_t stream)
{
  const int*   idx    = (const int*)  d_in[0];
  const float* wte    = (const float*)d_in[1];
  const float* wpe    = (const float*)d_in[2];
  const float* ln1_w  = (const float*)d_in[3];
  const float* ln1_b  = (const float*)d_in[4];
  const float* qkv_w  = (const float*)d_in[5];
  const float* qkv_b  = (const float*)d_in[6];
  const float* out_w  = (const float*)d_in[7];
  const float* out_b  = (const float*)d_in[8];
  const float* ln2_w  = (const float*)d_in[9];
  const float* ln2_b  = (const float*)d_in[10];
  const float* fc1_w  = (const float*)d_in[11];
  const float* fc1_b  = (const float*)d_in[12];
  const float* fc2_w  = (const float*)d_in[13];
  const float* fc2_b  = (const float*)d_in[14];
  const float* lnf_w  = (const float*)d_in[15];
  const float* lnf_b  = (const float*)d_in[16];
  const float* head_w = (const float*)d_in[17];
  const float* head_b = (const float*)d_in[18];

  char* ws = (char*)d_ws;
  float* x    = (float*)(ws + 0);            // 4096x1024 f32   16777216
  u16*   h    = (u16*)  (ws + 16777216);     // 4096x1024 bf16   8388608
  u16*   qkvb = (u16*)  (ws + 25165824);     // 4096x3072 bf16  25165824
  u16*   y    = (u16*)  (ws + 50331648);     // 4096x1024 bf16   8388608
  u16*   g    = (u16*)  (ws + 58720256);     // 4096x4096 bf16  33554432
  u16*   wq   = (u16*)  (ws + 92274688);     // 3072x1024 bf16   6291456
  u16*   wo   = (u16*)  (ws + 98566144);     // 1024x1024 bf16   2097152
  u16*   w1   = (u16*)  (ws + 100663296);    // 4096x1024 bf16   8388608
  u16*   w2   = (u16*)  (ws + 109051904);    // 1024x4096 bf16   8388608
  u16*   wh   = (u16*)  (ws + 117440512);    // 1024x1024 bf16   2097152
  float* hbp  = (float*)(ws + 119537664);    // 1024 f32            4096
  // total: 119541760 bytes (~114 MiB)

  constexpr int LDS_BIG = 4 * (512 * 32) * 2;     // 131072 (qkv 128x384, fc1 256x256)
  constexpr int LDS_SML = 4 * (256 * 32) * 2;     // 65536 -> 2 blocks/CU
  hipFuncSetAttribute((const void*)gemm2_kernel<EPI_BF16, 8, 4, 2, 3, 2>,
                      hipFuncAttributeMaxDynamicSharedMemorySize, LDS_BIG);
  hipFuncSetAttribute((const void*)gemm2_kernel<EPI_GELU, 8, 4, 4, 2, 2>,
                      hipFuncAttributeMaxDynamicSharedMemorySize, LDS_BIG);
  hipFuncSetAttribute((const void*)gemm2_kernel<EPI_RESID, 4, 2, 2, 2, 2>,
                      hipFuncAttributeMaxDynamicSharedMemorySize, LDS_SML);
  hipFuncSetAttribute((const void*)gemm2_kernel<EPI_OUT, 4, 2, 2, 2, 2>,
                      hipFuncAttributeMaxDynamicSharedMemorySize, LDS_SML);

  embed_kernel<<<MTOK, 256, 0, stream>>>(idx, wte, wpe, x);
  biaspad_kernel<<<4, 256, 0, stream>>>(head_b, hbp);

  for (int l = 0; l < NL; l++){
    ln_kernel<<<MTOK, 256, 0, stream>>>(x, ln1_w + l * E, ln1_b + l * E, h);
    wconv4_kernel<<<3072, 256, 0, stream>>>(
        qkv_w + (size_t)l * E * 3 * E, out_w + (size_t)l * E * E,
        fc1_w + (size_t)l * E * HID, fc2_w + (size_t)l * HID * E,
        wq, nullptr, w1, w2, wo);
    // qkv: BM=128, BN=384 -> grid (3072/384, 4096/128) = (8, 32) = 256 blocks
    gemm2_kernel<EPI_BF16, 8, 4, 2, 3, 2><<<dim3(8, 32), 512, LDS_BIG, stream>>>(
        h, wq, qkv_b + (size_t)l * 3 * E, qkvb, nullptr, MTOK, 3 * E, E);
    attn_kernel<<<dim3(8, NH, NB), 256, 0, stream>>>(qkvb, y);
    gemm2_kernel<EPI_RESID, 4, 2, 2, 2, 2><<<dim3(8, 32), 256, LDS_SML, stream>>>(
        y, wo, out_b + (size_t)l * E, nullptr, x, MTOK, E, E);
    ln_kernel<<<MTOK, 256, 0, stream>>>(x, ln2_w + l * E, ln2_b + l * E, h);
    // fc1: BM=256, BN=256 -> grid (16, 16) = 256 blocks
    gemm2_kernel<EPI_GELU, 8, 4, 4, 2, 2><<<dim3(16, 16), 512, LDS_BIG, stream>>>(
        h, w1, fc1_b + (size_t)l * HID, g, nullptr, MTOK, HID, E);
    gemm2_kernel<EPI_RESID, 4, 2, 2, 2, 2><<<dim3(8, 32), 256, LDS_SML, stream>>>(
        g, w2, fc2_b + (size_t)l * E, nullptr, x, MTOK, E, HID);
  }
  ln_kernel<<<MTOK, 256, 0, stream>>>(x, lnf_w, lnf_b, h);
  wconv_kernel<<<dim3(16, 16), 256, 0, stream>>>(head_w, wh, E, VOC, E);
  gemm2_kernel<EPI_OUT, 4, 2, 2, 2, 2><<<dim3(8, 32), 256, LDS_SML, stream>>>(
      h, wh, hbp, (float*)d_out, nullptr, MTOK, E, E);
}

// Round 16
// 1873.407 us; speedup vs baseline: 1.0614x; 1.0614x over previous
//
#include <hip/hip_runtime.h>
#include <math.h>

// GPT fwd: B=4, S=1024, L=8, H=16, E=1024, D=64, HID=4096, V=1000
// Workspace requirement: ~120 MB (see offsets below).

typedef unsigned short u16;
typedef unsigned int u32;
typedef __attribute__((ext_vector_type(4))) float f32x4;
typedef __attribute__((ext_vector_type(8))) __bf16 bf16x8;
typedef __attribute__((ext_vector_type(8))) u16 u16x8;
typedef __attribute__((ext_vector_type(4))) u16 u16x4;

#define E 1024
#define HID 4096
#define NH 16
#define HD 64
#define SEQ 1024
#define NB 4
#define NL 8
#define MTOK 4096
#define VOC 1000

#define VMCNT(n) asm volatile("s_waitcnt vmcnt(" #n ")" ::: "memory")

__device__ __forceinline__ u16 f2bf(float f){
  u32 u = __float_as_uint(f);
  u32 r = (u + 0x7fffu + ((u >> 16) & 1u)) >> 16;
  return (u16)r;
}
__device__ __forceinline__ float bf2f(u16 b){
  return __uint_as_float((u32)b << 16);
}
__device__ __forceinline__ bf16x8 ld_bf8(const u16* p){
  return *reinterpret_cast<const bf16x8*>(p);
}
__device__ __forceinline__ bf16x8 as_bf(u16x8 v){
  return __builtin_bit_cast(bf16x8, v);
}

// async global->LDS, 16B per lane; LDS dest = wave-uniform base + lane*16 (HW)
__device__ __forceinline__ void gload16(const void* g, void* l){
  __builtin_amdgcn_global_load_lds(
      (const __attribute__((address_space(1))) void*)g,
      (__attribute__((address_space(3))) void*)l, 16, 0, 0);
}

// ---------------- embed: x = wte[idx] + wpe[s] ----------------
__global__ __launch_bounds__(256) void embed_kernel(
    const int* __restrict__ idx, const float* __restrict__ wte,
    const float* __restrict__ wpe, float* __restrict__ x)
{
  int tok = blockIdx.x, tid = threadIdx.x;
  int id = idx[tok];
  int s = tok & (SEQ - 1);
  f32x4 a = *reinterpret_cast<const f32x4*>(&wte[(size_t)id * E + tid * 4]);
  f32x4 p = *reinterpret_cast<const f32x4*>(&wpe[(size_t)s * E + tid * 4]);
  f32x4 r = a + p;
  *reinterpret_cast<f32x4*>(&x[(size_t)tok * E + tid * 4]) = r;
}

// ---------------- layernorm: h = LN(x)*w + b (bf16 out) ----------------
__global__ __launch_bounds__(256) void ln_kernel(
    const float* __restrict__ x, const float* __restrict__ w,
    const float* __restrict__ b, u16* __restrict__ h)
{
  int row = blockIdx.x, tid = threadIdx.x;
  const float* xr = x + (size_t)row * E;
  f32x4 v = *reinterpret_cast<const f32x4*>(xr + tid * 4);
  float s = v[0] + v[1] + v[2] + v[3];
  float q = v[0]*v[0] + v[1]*v[1] + v[2]*v[2] + v[3]*v[3];
  #pragma unroll
  for (int mm = 1; mm < 64; mm <<= 1){
    s += __shfl_xor(s, mm);
    q += __shfl_xor(q, mm);
  }
  __shared__ float red[8];
  int wv = tid >> 6;
  if ((tid & 63) == 0){ red[wv] = s; red[4 + wv] = q; }
  __syncthreads();
  s = red[0] + red[1] + red[2] + red[3];
  q = red[4] + red[5] + red[6] + red[7];
  float mean = s * (1.0f / E);
  float var = q * (1.0f / E) - mean * mean;
  float rstd = rsqrtf(var + 1e-5f);
  f32x4 wv4 = *reinterpret_cast<const f32x4*>(w + tid * 4);
  f32x4 bv4 = *reinterpret_cast<const f32x4*>(b + tid * 4);
  u16 o0 = f2bf((v[0] - mean) * rstd * wv4[0] + bv4[0]);
  u16 o1 = f2bf((v[1] - mean) * rstd * wv4[1] + bv4[1]);
  u16 o2 = f2bf((v[2] - mean) * rstd * wv4[2] + bv4[2]);
  u16 o3 = f2bf((v[3] - mean) * rstd * wv4[3] + bv4[3]);
  u16* hp = &h[(size_t)row * E + tid * 4];
  hp[0] = o0; hp[1] = o1; hp[2] = o2; hp[3] = o3;
}

// ------- merged per-layer weight convert+transpose (all Nsrc % 64 == 0) -------
__global__ __launch_bounds__(256) void wconv4_kernel(
    const float* __restrict__ qw, const float* __restrict__ ow,
    const float* __restrict__ f1, const float* __restrict__ f2,
    u16* __restrict__ dq, u16* __restrict__ d_unused, u16* __restrict__ d1,
    u16* __restrict__ d2, u16* __restrict__ dw_out)
{
  const int bid = blockIdx.x, tid = threadIdx.x;
  const float* W; u16* Wt; int K, Nsrc, nx, base;
  if (bid < 768)      { W = qw; Wt = dq;     K = 1024; Nsrc = 3072; nx = 48; base = 0; }
  else if (bid < 1024){ W = ow; Wt = dw_out; K = 1024; Nsrc = 1024; nx = 16; base = 768; }
  else if (bid < 2048){ W = f1; Wt = d1;     K = 1024; Nsrc = 4096; nx = 64; base = 1024; }
  else                { W = f2; Wt = d2;     K = 4096; Nsrc = 1024; nx = 16; base = 2048; }
  const int t = bid - base;
  const int n0 = (t % nx) * 64, k0 = (t / nx) * 64;

  __shared__ float T[64][65];
  const int c = (tid & 15) * 4, rbase = tid >> 4;
  #pragma unroll
  for (int p = 0; p < 4; p++){
    int r = rbase + p * 16;
    f32x4 v = *reinterpret_cast<const f32x4*>(&W[(size_t)(k0 + r) * Nsrc + n0 + c]);
    T[r][c] = v[0]; T[r][c+1] = v[1]; T[r][c+2] = v[2]; T[r][c+3] = v[3];
  }
  __syncthreads();
  const int nr = tid >> 2, ks = (tid & 3) * 16;
  u16x8 o0, o1;
  #pragma unroll
  for (int i = 0; i < 8; i++){
    o0[i] = f2bf(T[ks + i][nr]);
    o1[i] = f2bf(T[ks + 8 + i][nr]);
  }
  u16* dst = &Wt[(size_t)(n0 + nr) * K + k0 + ks];
  *reinterpret_cast<u16x8*>(dst) = o0;
  *reinterpret_cast<u16x8*>(dst + 8) = o1;
}

// ------- single weight convert+transpose (head: Nsrc=1000 padded to 1024) -----
__global__ __launch_bounds__(256) void wconv_kernel(
    const float* __restrict__ W, u16* __restrict__ Wt,
    int K, int Nsrc, int N)
{
  __shared__ float T[64][65];
  const int tid = threadIdx.x;
  const int n0 = blockIdx.x * 64, k0 = blockIdx.y * 64;
  const int c = (tid & 15) * 4, rbase = tid >> 4;
  #pragma unroll
  for (int p = 0; p < 4; p++){
    int r = rbase + p * 16;
    #pragma unroll
    for (int j = 0; j < 4; j++){
      int n = n0 + c + j;
      T[r][c + j] = (n < Nsrc) ? W[(size_t)(k0 + r) * Nsrc + n] : 0.0f;
    }
  }
  __syncthreads();
  const int nr = tid >> 2, ks = (tid & 3) * 16;
  u16x8 o0, o1;
  #pragma unroll
  for (int i = 0; i < 8; i++){
    o0[i] = f2bf(T[ks + i][nr]);
    o1[i] = f2bf(T[ks + 8 + i][nr]);
  }
  u16* dst = &Wt[(size_t)(n0 + nr) * K + k0 + ks];
  *reinterpret_cast<u16x8*>(dst) = o0;
  *reinterpret_cast<u16x8*>(dst + 8) = o1;
}

// ---------------- GEMM: C = A(bf16)[M,K] @ Wt(bf16)[N,K]^T + bias ----------------
// NS=4 ring, BK=32, phase split (r13):
//   [ds_read frags(c) -> counted VMCNT -> s_barrier -> setprio+MFMA(c) -> STAGE(c+3)]
// Uniform staging RPW in {3,4}; non-uniform (BM=256/BN=192): waves 0-3 stage 4 A,
// waves 4-7 stage 3 B; counted vmcnt uses the wave's own loads-per-chunk.
// T1 XCD swizzle, T2 16B-slot XOR swizzle, T5 setprio.
enum { EPI_BF16 = 0, EPI_GELU = 1, EPI_RESID = 2, EPI_OUT = 3 };

template<int EPI, int NW, int NWX, int FM, int FN, int MINW>
__global__ __launch_bounds__(NW * 64, MINW) void gemm2_kernel(
    const u16* __restrict__ A, const u16* __restrict__ Wt,
    const float* __restrict__ bias, void* __restrict__ outp,
    float* __restrict__ xres, int M, int N, int K)
{
  constexpr int BM = FM * 16 * (NW / NWX);
  constexpr int BN = FN * 16 * NWX;
  constexpr int SLOT = (BM + BN) * 32;       // u16 per slot (A | B), BK=32
  constexpr int GROUPS = (BM + BN) / 16;
  constexpr bool UNI = (GROUPS % NW) == 0;
  constexpr int RPW = UNI ? GROUPS / NW : 0; // uniform groups per wave
  constexpr int NS = 4;
  extern __shared__ u16 lds[];               // NS * SLOT * 2 bytes

  const int tid = threadIdx.x;
  const int lane = tid & 63, w = tid >> 6;
  const int l15 = lane & 15, g = lane >> 4;
  const int wr = w / NWX, wc = w % NWX;
  const int wrbase = wr * FM * 16, wcbase = wc * FN * 16;

  // T1: bijective XCD swizzle (all grids have nwg % 8 == 0)
  const int nwgx = gridDim.x;
  const int bid = blockIdx.y * nwgx + blockIdx.x;
  const int cpx = (nwgx * gridDim.y) >> 3;
  const int swz = (bid & 7) * cpx + (bid >> 3);
  const int bm = (swz / nwgx) * BM, bn = (swz % nwgx) * BN;

  const u16* Abase = A + (size_t)bm * K;
  const u16* Bbase = Wt + (size_t)bn * K;

  f32x4 acc[FM][FN];
  #pragma unroll
  for (int i = 0; i < FM; i++)
    #pragma unroll
    for (int j = 0; j < FN; j++)
      acc[i][j] = f32x4{0.f, 0.f, 0.f, 0.f};

  // stage chunk cc into slot s. LDS linear [row][32k]; source 16B-slot pre-swizzled.
  const int lr = lane >> 2, ps = lane & 3;
  const int ss = ps ^ ((lane >> 4) & 3);     // (row>>2)&3 == (lane>>4)&3 (base%16==0)
  auto STAGE = [&](int s, int cc){
    const int k0 = cc * 32;
    u16* As = lds + s * SLOT;
    u16* Bs = As + BM * 32;
    if constexpr (UNI){
      #pragma unroll
      for (int j = 0; j < RPW; j++){
        int base = (w * RPW + j) * 16;
        if (base < BM){
          gload16(&Abase[(size_t)(base + lr) * K + k0 + ss * 8], As + base * 32);
        } else {
          int rb = base - BM;
          gload16(&Bbase[(size_t)(rb + lr) * K + k0 + ss * 8], Bs + rb * 32);
        }
      }
    } else {
      // BM=256 (16 A-groups), BN=192 (12 B-groups): w<4 -> 4 A; w>=4 -> 3 B
      static_assert(BM == 256 && BN == 192, "non-uniform path is specialized");
      if (w < 4){
        #pragma unroll
        for (int j = 0; j < 4; j++){
          int base = (w * 4 + j) * 16;
          gload16(&Abase[(size_t)(base + lr) * K + k0 + ss * 8], As + base * 32);
        }
      } else {
        #pragma unroll
        for (int j = 0; j < 3; j++){
          int rb = ((w - 4) * 3 + j) * 16;
          gload16(&Bbase[(size_t)(rb + lr) * K + k0 + ss * 8], Bs + rb * 32);
        }
      }
    }
  };
  // counted wait: allow the newest chunk's loads (this wave's count) to stay in flight
  auto WAIT1 = [&](){
    if constexpr (UNI){
      static_assert(!UNI || RPW == 4 || RPW == 3, "vmcnt literal covers RPW 3/4");
      if constexpr (RPW == 4) { VMCNT(4); } else { VMCNT(3); }
    } else {
      if (w < 4) { VMCNT(4); } else { VMCNT(3); }
    }
  };

  const int nt = K >> 5;                     // >= 32 for all our shapes
  STAGE(0, 0); STAGE(1, 1); STAGE(2, 2);
  WAIT1();                                   // chunks 0,1 landed (chunk 2 in flight)
  __builtin_amdgcn_sched_barrier(0);
  __builtin_amdgcn_s_barrier();
  __builtin_amdgcn_sched_barrier(0);

  int sl = 0;
  for (int c = 0; c < nt; c++){
    // ---- ds_read frags of chunk c (visible since previous barrier) ----
    const u16* As = lds + sl * SLOT;
    const u16* Bs = As + BM * 32;
    bf16x8 af[FM], bf[FN];
    const int rsw = (g ^ (l15 >> 2)) * 8;    // swizzled 16B slot on read
    #pragma unroll
    for (int mf = 0; mf < FM; mf++)
      af[mf] = ld_bf8(&As[(wrbase + mf * 16 + l15) * 32 + rsw]);
    #pragma unroll
    for (int nf = 0; nf < FN; nf++)
      bf[nf] = ld_bf8(&Bs[(wcbase + nf * 16 + l15) * 32 + rsw]);
    __builtin_amdgcn_sched_barrier(0);
    // ---- counted vmcnt: chunk c+1 landed before the barrier releases ----
    if (c + 2 <= nt - 1) { WAIT1(); } else { VMCNT(0); }
    __builtin_amdgcn_sched_barrier(0);
    __builtin_amdgcn_s_barrier();            // chunk c+1 visible; reads of c issued
    __builtin_amdgcn_sched_barrier(0);
    // ---- MFMA ----
    __builtin_amdgcn_s_setprio(1);
    #pragma unroll
    for (int mf = 0; mf < FM; mf++)
      #pragma unroll
      for (int nf = 0; nf < FN; nf++)
        acc[mf][nf] = __builtin_amdgcn_mfma_f32_16x16x32_bf16(
            af[mf], bf[nf], acc[mf][nf], 0, 0, 0);
    __builtin_amdgcn_s_setprio(0);
    // ---- prefetch chunk c+3 into slot (c-1)%4 (dead once waves passed barrier(c)) ----
    if (c + 3 < nt){
      int s2 = sl + 3; if (s2 >= NS) s2 -= NS;
      STAGE(s2, c + 3);
    }
    sl++; if (sl >= NS) sl -= NS;
  }

  // epilogue (C/D: col = lane&15, row = (lane>>4)*4 + reg)
  #pragma unroll
  for (int mf = 0; mf < FM; mf++){
    #pragma unroll
    for (int nf = 0; nf < FN; nf++){
      int col = bn + wcbase + nf * 16 + l15;
      float bv = bias[col];
      #pragma unroll
      for (int r = 0; r < 4; r++){
        int row = bm + wrbase + mf * 16 + g * 4 + r;
        float v = acc[mf][nf][r] + bv;
        if constexpr (EPI == EPI_BF16){
          ((u16*)outp)[(size_t)row * N + col] = f2bf(v);
        } else if constexpr (EPI == EPI_GELU){
          ((u16*)outp)[(size_t)row * N + col] =
              f2bf(0.5f * v * (1.0f + erff(v * 0.70710678118654752f)));
        } else if constexpr (EPI == EPI_RESID){
          xres[(size_t)row * N + col] += v;
        } else {
          if (col < VOC)
            ((float*)outp)[(size_t)row * VOC + col] = v;
        }
      }
    }
  }
}

// ---------------- flash attention (causal), paired 64-row q-blocks ----------------
__global__ __launch_bounds__(256) void attn_kernel(
    const u16* __restrict__ qkv, u16* __restrict__ y)
{
  __shared__ u16 Kl[64 * 64];       // [key][dslot swizzled], 8KB
  __shared__ u16 Vt[64 * 72];       // [d][c'], stride 72, 9KB
  __shared__ u16 Pl[4 * 16 * 72];   // per-wave [q][c'], 9KB
  const int pr = blockIdx.x, hh = blockIdx.y, b = blockIdx.z;
  const int tid = threadIdx.x;
  const int lane = tid & 63, w = tid >> 6;
  const int l15 = lane & 15, g = lane >> 4;
  const size_t tokbase = (size_t)b * SEQ;
  const int qstart[2] = { pr * 64, (15 - pr) * 64 };

  int qbase[2], dt[2];
  u16x8 q0[2], q1[2];
  f32x4 o[2][4];
  float m[2][4], llp[2][4];
  #pragma unroll
  for (int st = 0; st < 2; st++){
    qbase[st] = qstart[st] + w * 16;
    dt[st] = qbase[st] >> 6;
    const u16* qp = &qkv[(tokbase + qbase[st] + l15) * (3 * E) + hh * HD];
    u16x8 ra = *reinterpret_cast<const u16x8*>(&qp[g * 8]);
    u16x8 rb = *reinterpret_cast<const u16x8*>(&qp[32 + g * 8]);
    #pragma unroll
    for (int j = 0; j < 8; j++){
      q0[st][j] = f2bf(bf2f(ra[j]) * 0.125f);
      q1[st][j] = f2bf(bf2f(rb[j]) * 0.125f);
    }
    #pragma unroll
    for (int dc = 0; dc < 4; dc++) o[st][dc] = f32x4{0.f, 0.f, 0.f, 0.f};
    #pragma unroll
    for (int r = 0; r < 4; r++){ m[st][r] = -1e30f; llp[st][r] = 0.f; }
  }

  u16* Pw = &Pl[w * 16 * 72];
  const int T = 16 - pr;

  for (int t = 0; t < T; t++){
    const int k0 = t * 64;
    __syncthreads();
    #pragma unroll
    for (int j = 0; j < 2; j++){
      int row = w * 16 + j * 8 + (lane >> 3);
      int sl = lane & 7;
      const u16* src = &qkv[(tokbase + k0 + row) * (3 * E) + E + hh * HD
                            + ((sl ^ (row & 7)) * 8)];
      gload16(src, &Kl[w * 1024 + j * 512]);
    }
    {
      int d0 = (tid & 15) * 4;
      int s  = tid >> 4;
      #pragma unroll
      for (int mh = 0; mh < 2; mh++){
        int kA = s + 32 * mh;
        const u16* vpA = &qkv[(tokbase + k0 + kA) * (3 * E) + 2 * E + hh * HD + d0];
        const u16* vpB = vpA + 16 * (3 * E);
        u16x4 va = *reinterpret_cast<const u16x4*>(vpA);
        u16x4 vb = *reinterpret_cast<const u16x4*>(vpB);
        #pragma unroll
        for (int i = 0; i < 4; i++)
          *reinterpret_cast<u32*>(&Vt[(d0 + i) * 72 + 4 * s + 2 * mh]) =
              (u32)va[i] | ((u32)vb[i] << 16);
      }
    }
    __syncthreads();

    #pragma unroll
    for (int st = 0; st < 2; st++){
      if (t > dt[st]) continue;
      const bool diag = (t == dt[st]);
      f32x4 s[4];
      #pragma unroll
      for (int kg = 0; kg < 4; kg++){
        int key = kg * 16 + l15;
        const u16* kb = &Kl[key * 64];
        bf16x8 k0f = ld_bf8(&kb[(g ^ (key & 7)) * 8]);
        bf16x8 k1f = ld_bf8(&kb[((4 + g) ^ (key & 7)) * 8]);
        f32x4 z = f32x4{0.f, 0.f, 0.f, 0.f};
        z = __builtin_amdgcn_mfma_f32_16x16x32_bf16(as_bf(q0[st]), k0f, z, 0, 0, 0);
        z = __builtin_amdgcn_mfma_f32_16x16x32_bf16(as_bf(q1[st]), k1f, z, 0, 0, 0);
        s[kg] = z;
      }
      if (diag){
        #pragma unroll
        for (int kg = 0; kg < 4; kg++){
          int key = k0 + kg * 16 + l15;
          #pragma unroll
          for (int r = 0; r < 4; r++){
            int q = qbase[st] + g * 4 + r;
            s[kg][r] = (key <= q) ? s[kg][r] : -1e9f;
          }
        }
      }
      float lmax[4];
      bool need = false;
      #pragma unroll
      for (int r = 0; r < 4; r++){
        lmax[r] = fmaxf(fmaxf(s[0][r], s[1][r]), fmaxf(s[2][r], s[3][r]));
        need = need || (lmax[r] > m[st][r] + 8.0f);
      }
      if (__any(need)){
        #pragma unroll
        for (int r = 0; r < 4; r++){
          float x = lmax[r];
          x = fmaxf(x, __shfl_xor(x, 1));
          x = fmaxf(x, __shfl_xor(x, 2));
          x = fmaxf(x, __shfl_xor(x, 4));
          x = fmaxf(x, __shfl_xor(x, 8));
          float mn = fmaxf(m[st][r], x);
          float al = __expf(m[st][r] - mn);
          m[st][r] = mn;
          llp[st][r] *= al;
          #pragma unroll
          for (int dc = 0; dc < 4; dc++) o[st][dc][r] *= al;
        }
      }
      #pragma unroll
      for (int r = 0; r < 4; r++){
        float p0 = __expf(s[0][r] - m[st][r]);
        float p1 = __expf(s[1][r] - m[st][r]);
        float p2 = __expf(s[2][r] - m[st][r]);
        float p3 = __expf(s[3][r] - m[st][r]);
        llp[st][r] += (p0 + p1) + (p2 + p3);
        u16x4 pp = { f2bf(p0), f2bf(p1), f2bf(p2), f2bf(p3) };
        *reinterpret_cast<u16x4*>(&Pw[(g * 4 + r) * 72 + 4 * l15]) = pp;
      }
      bf16x8 pa0 = ld_bf8(&Pw[l15 * 72 + g * 8]);
      bf16x8 pa1 = ld_bf8(&Pw[l15 * 72 + 32 + g * 8]);
      #pragma unroll
      for (int dc = 0; dc < 4; dc++){
        bf16x8 v0 = ld_bf8(&Vt[(dc * 16 + l15) * 72 + g * 8]);
        bf16x8 v1 = ld_bf8(&Vt[(dc * 16 + l15) * 72 + 32 + g * 8]);
        o[st][dc] = __builtin_amdgcn_mfma_f32_16x16x32_bf16(pa0, v0, o[st][dc], 0, 0, 0);
        o[st][dc] = __builtin_amdgcn_mfma_f32_16x16x32_bf16(pa1, v1, o[st][dc], 0, 0, 0);
      }
    }
  }

  #pragma unroll
  for (int st = 0; st < 2; st++){
    #pragma unroll
    for (int r = 0; r < 4; r++){
      float rs = llp[st][r];
      rs += __shfl_xor(rs, 1);
      rs += __shfl_xor(rs, 2);
      rs += __shfl_xor(rs, 4);
      rs += __shfl_xor(rs, 8);
      float inv = 1.0f / rs;
      int row = qbase[st] + g * 4 + r;
      #pragma unroll
      for (int dc = 0; dc < 4; dc++){
        int col = hh * HD + dc * 16 + l15;
        y[(tokbase + row) * E + col] = f2bf(o[st][dc][r] * inv);
      }
    }
  }
}

// ---------------- head bias pad [1000] -> [1024] f32 ----------------
__global__ __launch_bounds__(256) void biaspad_kernel(
    const float* __restrict__ hb, float* __restrict__ bpad)
{
  int i = blockIdx.x * 256 + threadIdx.x;
  if (i < 1024) bpad[i] = (i < VOC) ? hb[i] : 0.0f;
}

// ---------------- launch ----------------
extern "C" void kernel_launch(void* const* d_in, const int* in_sizes, int n_in,
                              void* d_out, int out_size, void* d_ws, size_t ws_size,
                              hipStream_t stream)
{
  const int*   idx    = (const int*)  d_in[0];
  const float* wte    = (const float*)d_in[1];
  const float* wpe    = (const float*)d_in[2];
  const float* ln1_w  = (const float*)d_in[3];
  const float* ln1_b  = (const float*)d_in[4];
  const float* qkv_w  = (const float*)d_in[5];
  const float* qkv_b  = (const float*)d_in[6];
  const float* out_w  = (const float*)d_in[7];
  const float* out_b  = (const float*)d_in[8];
  const float* ln2_w  = (const float*)d_in[9];
  const float* ln2_b  = (const float*)d_in[10];
  const float* fc1_w  = (const float*)d_in[11];
  const float* fc1_b  = (const float*)d_in[12];
  const float* fc2_w  = (const float*)d_in[13];
  const float* fc2_b  = (const float*)d_in[14];
  const float* lnf_w  = (const float*)d_in[15];
  const float* lnf_b  = (const float*)d_in[16];
  const float* head_w = (const float*)d_in[17];
  const float* head_b = (const float*)d_in[18];

  char* ws = (char*)d_ws;
  float* x    = (float*)(ws + 0);            // 4096x1024 f32   16777216
  u16*   h    = (u16*)  (ws + 16777216);     // 4096x1024 bf16   8388608
  u16*   qkvb = (u16*)  (ws + 25165824);     // 4096x3072 bf16  25165824
  u16*   y    = (u16*)  (ws + 50331648);     // 4096x1024 bf16   8388608
  u16*   g    = (u16*)  (ws + 58720256);     // 4096x4096 bf16  33554432
  u16*   wq   = (u16*)  (ws + 92274688);     // 3072x1024 bf16   6291456
  u16*   wo   = (u16*)  (ws + 98566144);     // 1024x1024 bf16   2097152
  u16*   w1   = (u16*)  (ws + 100663296);    // 4096x1024 bf16   8388608
  u16*   w2   = (u16*)  (ws + 109051904);    // 1024x4096 bf16   8388608
  u16*   wh   = (u16*)  (ws + 117440512);    // 1024x1024 bf16   2097152
  float* hbp  = (float*)(ws + 119537664);    // 1024 f32            4096
  // total: 119541760 bytes (~114 MiB)

  constexpr int LDS_QKV = 4 * (448 * 32) * 2;     // 114688 bytes (BM256/BN192)
  constexpr int LDS_BIG = 4 * (512 * 32) * 2;     // 131072 bytes (BM256/BN256)
  constexpr int LDS_SML = 4 * (192 * 32) * 2;     // 49152 bytes (BM128/BN64) -> 3/CU cap
  hipFuncSetAttribute((const void*)gemm2_kernel<EPI_BF16, 8, 4, 8, 3, 2>,
                      hipFuncAttributeMaxDynamicSharedMemorySize, LDS_QKV);
  hipFuncSetAttribute((const void*)gemm2_kernel<EPI_GELU, 8, 4, 8, 4, 2>,
                      hipFuncAttributeMaxDynamicSharedMemorySize, LDS_BIG);
  hipFuncSetAttribute((const void*)gemm2_kernel<EPI_RESID, 4, 2, 4, 2, 2>,
                      hipFuncAttributeMaxDynamicSharedMemorySize, LDS_SML);
  hipFuncSetAttribute((const void*)gemm2_kernel<EPI_OUT, 4, 2, 4, 2, 2>,
                      hipFuncAttributeMaxDynamicSharedMemorySize, LDS_SML);

  embed_kernel<<<MTOK, 256, 0, stream>>>(idx, wte, wpe, x);
  biaspad_kernel<<<4, 256, 0, stream>>>(head_b, hbp);

  for (int l = 0; l < NL; l++){
    ln_kernel<<<MTOK, 256, 0, stream>>>(x, ln1_w + l * E, ln1_b + l * E, h);
    wconv4_kernel<<<3072, 256, 0, stream>>>(
        qkv_w + (size_t)l * E * 3 * E, out_w + (size_t)l * E * E,
        fc1_w + (size_t)l * E * HID, fc2_w + (size_t)l * HID * E,
        wq, nullptr, w1, w2, wo);
    gemm2_kernel<EPI_BF16, 8, 4, 8, 3, 2><<<dim3(16, 16), 512, LDS_QKV, stream>>>(
        h, wq, qkv_b + (size_t)l * 3 * E, qkvb, nullptr, MTOK, 3 * E, E);
    attn_kernel<<<dim3(8, NH, NB), 256, 0, stream>>>(qkvb, y);
    // out-proj: BM=128, BN=64 -> grid (16, 32) = 512 blocks = 2/CU
    gemm2_kernel<EPI_RESID, 4, 2, 4, 2, 2><<<dim3(16, 32), 256, LDS_SML, stream>>>(
        y, wo, out_b + (size_t)l * E, nullptr, x, MTOK, E, E);
    ln_kernel<<<MTOK, 256, 0, stream>>>(x, ln2_w + l * E, ln2_b + l * E, h);
    gemm2_kernel<EPI_GELU, 8, 4, 8, 4, 2><<<dim3(16, 16), 512, LDS_BIG, stream>>>(
        h, w1, fc1_b + (size_t)l * HID, g, nullptr, MTOK, HID, E);
    gemm2_kernel<EPI_RESID, 4, 2, 4, 2, 2><<<dim3(16, 32), 256, LDS_SML, stream>>>(
        g, w2, fc2_b + (size_t)l * E, nullptr, x, MTOK, E, HID);
  }
  ln_kernel<<<MTOK, 256, 0, stream>>>(x, lnf_w, lnf_b, h);
  wconv_kernel<<<dim3(16, 16), 256, 0, stream>>>(head_w, wh, E, VOC, E);
  gemm2_kernel<EPI_OUT, 4, 2, 4, 2, 2><<<dim3(16, 32), 256, LDS_SML, stream>>>(
      h, wh, hbp, (float*)d_out, nullptr, MTOK, E, E);
}

// Round 17
// 1818.573 us; speedup vs baseline: 1.0934x; 1.0302x over previous
//
#include <hip/hip_runtime.h>
#include <math.h>

// GPT fwd: B=4, S=1024, L=8, H=16, E=1024, D=64, HID=4096, V=1000
// Workspace requirement: ~128 MB (see offsets below).

typedef unsigned short u16;
typedef unsigned int u32;
typedef __attribute__((ext_vector_type(4))) float f32x4;
typedef __attribute__((ext_vector_type(8))) __bf16 bf16x8;
typedef __attribute__((ext_vector_type(8))) u16 u16x8;
typedef __attribute__((ext_vector_type(4))) u16 u16x4;

#define E 1024
#define HID 4096
#define NH 16
#define HD 64
#define SEQ 1024
#define NB 4
#define NL 8
#define MTOK 4096
#define VOC 1000

#define VMCNT(n) asm volatile("s_waitcnt vmcnt(" #n ")" ::: "memory")

__device__ __forceinline__ u16 f2bf(float f){
  u32 u = __float_as_uint(f);
  u32 r = (u + 0x7fffu + ((u >> 16) & 1u)) >> 16;
  return (u16)r;
}
__device__ __forceinline__ float bf2f(u16 b){
  return __uint_as_float((u32)b << 16);
}
__device__ __forceinline__ bf16x8 ld_bf8(const u16* p){
  return *reinterpret_cast<const bf16x8*>(p);
}
__device__ __forceinline__ bf16x8 as_bf(u16x8 v){
  return __builtin_bit_cast(bf16x8, v);
}

// async global->LDS, 16B per lane; LDS dest = wave-uniform base + lane*16 (HW)
__device__ __forceinline__ void gload16(const void* g, void* l){
  __builtin_amdgcn_global_load_lds(
      (const __attribute__((address_space(1))) void*)g,
      (__attribute__((address_space(3))) void*)l, 16, 0, 0);
}

// ---------------- embed: x = wte[idx] + wpe[s] ----------------
__global__ __launch_bounds__(256) void embed_kernel(
    const int* __restrict__ idx, const float* __restrict__ wte,
    const float* __restrict__ wpe, float* __restrict__ x)
{
  int tok = blockIdx.x, tid = threadIdx.x;
  int id = idx[tok];
  int s = tok & (SEQ - 1);
  f32x4 a = *reinterpret_cast<const f32x4*>(&wte[(size_t)id * E + tid * 4]);
  f32x4 p = *reinterpret_cast<const f32x4*>(&wpe[(size_t)s * E + tid * 4]);
  f32x4 r = a + p;
  *reinterpret_cast<f32x4*>(&x[(size_t)tok * E + tid * 4]) = r;
}

// ---------------- layernorm: h = LN(x)*w + b (bf16 out) ----------------
__global__ __launch_bounds__(256) void ln_kernel(
    const float* __restrict__ x, const float* __restrict__ w,
    const float* __restrict__ b, u16* __restrict__ h)
{
  int row = blockIdx.x, tid = threadIdx.x;
  const float* xr = x + (size_t)row * E;
  f32x4 v = *reinterpret_cast<const f32x4*>(xr + tid * 4);
  float s = v[0] + v[1] + v[2] + v[3];
  float q = v[0]*v[0] + v[1]*v[1] + v[2]*v[2] + v[3]*v[3];
  #pragma unroll
  for (int mm = 1; mm < 64; mm <<= 1){
    s += __shfl_xor(s, mm);
    q += __shfl_xor(q, mm);
  }
  __shared__ float red[8];
  int wv = tid >> 6;
  if ((tid & 63) == 0){ red[wv] = s; red[4 + wv] = q; }
  __syncthreads();
  s = red[0] + red[1] + red[2] + red[3];
  q = red[4] + red[5] + red[6] + red[7];
  float mean = s * (1.0f / E);
  float var = q * (1.0f / E) - mean * mean;
  float rstd = rsqrtf(var + 1e-5f);
  f32x4 wv4 = *reinterpret_cast<const f32x4*>(w + tid * 4);
  f32x4 bv4 = *reinterpret_cast<const f32x4*>(b + tid * 4);
  u16 o0 = f2bf((v[0] - mean) * rstd * wv4[0] + bv4[0]);
  u16 o1 = f2bf((v[1] - mean) * rstd * wv4[1] + bv4[1]);
  u16 o2 = f2bf((v[2] - mean) * rstd * wv4[2] + bv4[2]);
  u16 o3 = f2bf((v[3] - mean) * rstd * wv4[3] + bv4[3]);
  u16* hp = &h[(size_t)row * E + tid * 4];
  hp[0] = o0; hp[1] = o1; hp[2] = o2; hp[3] = o3;
}

// ---- fused residual+LN: x += p (bf16); h = LN(x)*w + b; x written back ----
__global__ __launch_bounds__(256) void lnadd_kernel(
    float* __restrict__ x, const u16* __restrict__ p,
    const float* __restrict__ w, const float* __restrict__ b,
    u16* __restrict__ h)
{
  int row = blockIdx.x, tid = threadIdx.x;
  float* xr = x + (size_t)row * E;
  f32x4 v = *reinterpret_cast<const f32x4*>(xr + tid * 4);
  u16x4 pv = *reinterpret_cast<const u16x4*>(&p[(size_t)row * E + tid * 4]);
  v[0] += bf2f(pv[0]); v[1] += bf2f(pv[1]);
  v[2] += bf2f(pv[2]); v[3] += bf2f(pv[3]);
  *reinterpret_cast<f32x4*>(xr + tid * 4) = v;
  float s = v[0] + v[1] + v[2] + v[3];
  float q = v[0]*v[0] + v[1]*v[1] + v[2]*v[2] + v[3]*v[3];
  #pragma unroll
  for (int mm = 1; mm < 64; mm <<= 1){
    s += __shfl_xor(s, mm);
    q += __shfl_xor(q, mm);
  }
  __shared__ float red[8];
  int wv = tid >> 6;
  if ((tid & 63) == 0){ red[wv] = s; red[4 + wv] = q; }
  __syncthreads();
  s = red[0] + red[1] + red[2] + red[3];
  q = red[4] + red[5] + red[6] + red[7];
  float mean = s * (1.0f / E);
  float var = q * (1.0f / E) - mean * mean;
  float rstd = rsqrtf(var + 1e-5f);
  f32x4 wv4 = *reinterpret_cast<const f32x4*>(w + tid * 4);
  f32x4 bv4 = *reinterpret_cast<const f32x4*>(b + tid * 4);
  u16 o0 = f2bf((v[0] - mean) * rstd * wv4[0] + bv4[0]);
  u16 o1 = f2bf((v[1] - mean) * rstd * wv4[1] + bv4[1]);
  u16 o2 = f2bf((v[2] - mean) * rstd * wv4[2] + bv4[2]);
  u16 o3 = f2bf((v[3] - mean) * rstd * wv4[3] + bv4[3]);
  u16* hp = &h[(size_t)row * E + tid * 4];
  hp[0] = o0; hp[1] = o1; hp[2] = o2; hp[3] = o3;
}

// ------- merged per-layer weight convert+transpose (all Nsrc % 64 == 0) -------
__global__ __launch_bounds__(256) void wconv4_kernel(
    const float* __restrict__ qw, const float* __restrict__ ow,
    const float* __restrict__ f1, const float* __restrict__ f2,
    u16* __restrict__ dq, u16* __restrict__ d_unused, u16* __restrict__ d1,
    u16* __restrict__ d2, u16* __restrict__ dw_out)
{
  const int bid = blockIdx.x, tid = threadIdx.x;
  const float* W; u16* Wt; int K, Nsrc, nx, base;
  if (bid < 768)      { W = qw; Wt = dq;     K = 1024; Nsrc = 3072; nx = 48; base = 0; }
  else if (bid < 1024){ W = ow; Wt = dw_out; K = 1024; Nsrc = 1024; nx = 16; base = 768; }
  else if (bid < 2048){ W = f1; Wt = d1;     K = 1024; Nsrc = 4096; nx = 64; base = 1024; }
  else                { W = f2; Wt = d2;     K = 4096; Nsrc = 1024; nx = 16; base = 2048; }
  const int t = bid - base;
  const int n0 = (t % nx) * 64, k0 = (t / nx) * 64;

  __shared__ float T[64][65];
  const int c = (tid & 15) * 4, rbase = tid >> 4;
  #pragma unroll
  for (int p = 0; p < 4; p++){
    int r = rbase + p * 16;
    f32x4 v = *reinterpret_cast<const f32x4*>(&W[(size_t)(k0 + r) * Nsrc + n0 + c]);
    T[r][c] = v[0]; T[r][c+1] = v[1]; T[r][c+2] = v[2]; T[r][c+3] = v[3];
  }
  __syncthreads();
  const int nr = tid >> 2, ks = (tid & 3) * 16;
  u16x8 o0, o1;
  #pragma unroll
  for (int i = 0; i < 8; i++){
    o0[i] = f2bf(T[ks + i][nr]);
    o1[i] = f2bf(T[ks + 8 + i][nr]);
  }
  u16* dst = &Wt[(size_t)(n0 + nr) * K + k0 + ks];
  *reinterpret_cast<u16x8*>(dst) = o0;
  *reinterpret_cast<u16x8*>(dst + 8) = o1;
}

// ------- single weight convert+transpose (head: Nsrc=1000 padded to 1024) -----
__global__ __launch_bounds__(256) void wconv_kernel(
    const float* __restrict__ W, u16* __restrict__ Wt,
    int K, int Nsrc, int N)
{
  __shared__ float T[64][65];
  const int tid = threadIdx.x;
  const int n0 = blockIdx.x * 64, k0 = blockIdx.y * 64;
  const int c = (tid & 15) * 4, rbase = tid >> 4;
  #pragma unroll
  for (int p = 0; p < 4; p++){
    int r = rbase + p * 16;
    #pragma unroll
    for (int j = 0; j < 4; j++){
      int n = n0 + c + j;
      T[r][c + j] = (n < Nsrc) ? W[(size_t)(k0 + r) * Nsrc + n] : 0.0f;
    }
  }
  __syncthreads();
  const int nr = tid >> 2, ks = (tid & 3) * 16;
  u16x8 o0, o1;
  #pragma unroll
  for (int i = 0; i < 8; i++){
    o0[i] = f2bf(T[ks + i][nr]);
    o1[i] = f2bf(T[ks + 8 + i][nr]);
  }
  u16* dst = &Wt[(size_t)(n0 + nr) * K + k0 + ks];
  *reinterpret_cast<u16x8*>(dst) = o0;
  *reinterpret_cast<u16x8*>(dst + 8) = o1;
}

// ---------------- GEMM: C = A(bf16)[M,K] @ Wt(bf16)[N,K]^T + bias ----------------
// NS=4 ring, BK=32, phase split (r13):
//   [ds_read frags(c) -> counted VMCNT -> s_barrier -> setprio+MFMA(c) -> STAGE(c+3)]
// Uniform staging RPW in {3,4}; non-uniform (BM=256/BN=192): waves 0-3 stage 4 A,
// waves 4-7 stage 3 B; counted vmcnt uses the wave's own loads-per-chunk.
// T1 XCD swizzle, T2 16B-slot XOR swizzle, T5 setprio.
enum { EPI_BF16 = 0, EPI_GELU = 1, EPI_OUT = 3 };

template<int EPI, int NW, int NWX, int FM, int FN, int MINW>
__global__ __launch_bounds__(NW * 64, MINW) void gemm2_kernel(
    const u16* __restrict__ A, const u16* __restrict__ Wt,
    const float* __restrict__ bias, void* __restrict__ outp,
    int M, int N, int K)
{
  constexpr int BM = FM * 16 * (NW / NWX);
  constexpr int BN = FN * 16 * NWX;
  constexpr int SLOT = (BM + BN) * 32;       // u16 per slot (A | B), BK=32
  constexpr int GROUPS = (BM + BN) / 16;
  constexpr bool UNI = (GROUPS % NW) == 0;
  constexpr int RPW = UNI ? GROUPS / NW : 0; // uniform groups per wave
  constexpr int NS = 4;
  extern __shared__ u16 lds[];               // NS * SLOT * 2 bytes

  const int tid = threadIdx.x;
  const int lane = tid & 63, w = tid >> 6;
  const int l15 = lane & 15, g = lane >> 4;
  const int wr = w / NWX, wc = w % NWX;
  const int wrbase = wr * FM * 16, wcbase = wc * FN * 16;

  // T1: bijective XCD swizzle (all grids have nwg % 8 == 0)
  const int nwgx = gridDim.x;
  const int bid = blockIdx.y * nwgx + blockIdx.x;
  const int cpx = (nwgx * gridDim.y) >> 3;
  const int swz = (bid & 7) * cpx + (bid >> 3);
  const int bm = (swz / nwgx) * BM, bn = (swz % nwgx) * BN;

  const u16* Abase = A + (size_t)bm * K;
  const u16* Bbase = Wt + (size_t)bn * K;

  f32x4 acc[FM][FN];
  #pragma unroll
  for (int i = 0; i < FM; i++)
    #pragma unroll
    for (int j = 0; j < FN; j++)
      acc[i][j] = f32x4{0.f, 0.f, 0.f, 0.f};

  // stage chunk cc into slot s. LDS linear [row][32k]; source 16B-slot pre-swizzled.
  const int lr = lane >> 2, ps = lane & 3;
  const int ss = ps ^ ((lane >> 4) & 3);     // (row>>2)&3 == (lane>>4)&3 (base%16==0)
  auto STAGE = [&](int s, int cc){
    const int k0 = cc * 32;
    u16* As = lds + s * SLOT;
    u16* Bs = As + BM * 32;
    if constexpr (UNI){
      #pragma unroll
      for (int j = 0; j < RPW; j++){
        int base = (w * RPW + j) * 16;
        if (base < BM){
          gload16(&Abase[(size_t)(base + lr) * K + k0 + ss * 8], As + base * 32);
        } else {
          int rb = base - BM;
          gload16(&Bbase[(size_t)(rb + lr) * K + k0 + ss * 8], Bs + rb * 32);
        }
      }
    } else {
      // BM=256 (16 A-groups), BN=192 (12 B-groups): w<4 -> 4 A; w>=4 -> 3 B
      static_assert(BM == 256 && BN == 192, "non-uniform path is specialized");
      if (w < 4){
        #pragma unroll
        for (int j = 0; j < 4; j++){
          int base = (w * 4 + j) * 16;
          gload16(&Abase[(size_t)(base + lr) * K + k0 + ss * 8], As + base * 32);
        }
      } else {
        #pragma unroll
        for (int j = 0; j < 3; j++){
          int rb = ((w - 4) * 3 + j) * 16;
          gload16(&Bbase[(size_t)(rb + lr) * K + k0 + ss * 8], Bs + rb * 32);
        }
      }
    }
  };
  // counted wait: allow the newest chunk's loads (this wave's count) to stay in flight
  auto WAIT1 = [&](){
    if constexpr (UNI){
      static_assert(!UNI || RPW == 4 || RPW == 3, "vmcnt literal covers RPW 3/4");
      if constexpr (RPW == 4) { VMCNT(4); } else { VMCNT(3); }
    } else {
      if (w < 4) { VMCNT(4); } else { VMCNT(3); }
    }
  };

  const int nt = K >> 5;                     // >= 32 for all our shapes
  STAGE(0, 0); STAGE(1, 1); STAGE(2, 2);
  WAIT1();                                   // chunks 0,1 landed (chunk 2 in flight)
  __builtin_amdgcn_sched_barrier(0);
  __builtin_amdgcn_s_barrier();
  __builtin_amdgcn_sched_barrier(0);

  int sl = 0;
  for (int c = 0; c < nt; c++){
    // ---- ds_read frags of chunk c (visible since previous barrier) ----
    const u16* As = lds + sl * SLOT;
    const u16* Bs = As + BM * 32;
    bf16x8 af[FM], bf[FN];
    const int rsw = (g ^ (l15 >> 2)) * 8;    // swizzled 16B slot on read
    #pragma unroll
    for (int mf = 0; mf < FM; mf++)
      af[mf] = ld_bf8(&As[(wrbase + mf * 16 + l15) * 32 + rsw]);
    #pragma unroll
    for (int nf = 0; nf < FN; nf++)
      bf[nf] = ld_bf8(&Bs[(wcbase + nf * 16 + l15) * 32 + rsw]);
    __builtin_amdgcn_sched_barrier(0);
    // ---- counted vmcnt: chunk c+1 landed before the barrier releases ----
    if (c + 2 <= nt - 1) { WAIT1(); } else { VMCNT(0); }
    __builtin_amdgcn_sched_barrier(0);
    __builtin_amdgcn_s_barrier();            // chunk c+1 visible; reads of c issued
    __builtin_amdgcn_sched_barrier(0);
    // ---- MFMA ----
    __builtin_amdgcn_s_setprio(1);
    #pragma unroll
    for (int mf = 0; mf < FM; mf++)
      #pragma unroll
      for (int nf = 0; nf < FN; nf++)
        acc[mf][nf] = __builtin_amdgcn_mfma_f32_16x16x32_bf16(
            af[mf], bf[nf], acc[mf][nf], 0, 0, 0);
    __builtin_amdgcn_s_setprio(0);
    // ---- prefetch chunk c+3 into slot (c-1)%4 (dead once waves passed barrier(c)) ----
    if (c + 3 < nt){
      int s2 = sl + 3; if (s2 >= NS) s2 -= NS;
      STAGE(s2, c + 3);
    }
    sl++; if (sl >= NS) sl -= NS;
  }

  // epilogue (C/D: col = lane&15, row = (lane>>4)*4 + reg)
  #pragma unroll
  for (int mf = 0; mf < FM; mf++){
    #pragma unroll
    for (int nf = 0; nf < FN; nf++){
      int col = bn + wcbase + nf * 16 + l15;
      float bv = bias[col];
      #pragma unroll
      for (int r = 0; r < 4; r++){
        int row = bm + wrbase + mf * 16 + g * 4 + r;
        float v = acc[mf][nf][r] + bv;
        if constexpr (EPI == EPI_BF16){
          ((u16*)outp)[(size_t)row * N + col] = f2bf(v);
        } else if constexpr (EPI == EPI_GELU){
          ((u16*)outp)[(size_t)row * N + col] =
              f2bf(0.5f * v * (1.0f + erff(v * 0.70710678118654752f)));
        } else {
          if (col < VOC)
            ((float*)outp)[(size_t)row * VOC + col] = v;
        }
      }
    }
  }
}

// ---------------- flash attention (causal), paired 64-row q-blocks ----------------
__global__ __launch_bounds__(256) void attn_kernel(
    const u16* __restrict__ qkv, u16* __restrict__ y)
{
  __shared__ u16 Kl[64 * 64];       // [key][dslot swizzled], 8KB
  __shared__ u16 Vt[64 * 72];       // [d][c'], stride 72, 9KB
  __shared__ u16 Pl[4 * 16 * 72];   // per-wave [q][c'], 9KB
  const int pr = blockIdx.x, hh = blockIdx.y, b = blockIdx.z;
  const int tid = threadIdx.x;
  const int lane = tid & 63, w = tid >> 6;
  const int l15 = lane & 15, g = lane >> 4;
  const size_t tokbase = (size_t)b * SEQ;
  const int qstart[2] = { pr * 64, (15 - pr) * 64 };

  int qbase[2], dt[2];
  u16x8 q0[2], q1[2];
  f32x4 o[2][4];
  float m[2][4], llp[2][4];
  #pragma unroll
  for (int st = 0; st < 2; st++){
    qbase[st] = qstart[st] + w * 16;
    dt[st] = qbase[st] >> 6;
    const u16* qp = &qkv[(tokbase + qbase[st] + l15) * (3 * E) + hh * HD];
    u16x8 ra = *reinterpret_cast<const u16x8*>(&qp[g * 8]);
    u16x8 rb = *reinterpret_cast<const u16x8*>(&qp[32 + g * 8]);
    #pragma unroll
    for (int j = 0; j < 8; j++){
      q0[st][j] = f2bf(bf2f(ra[j]) * 0.125f);
      q1[st][j] = f2bf(bf2f(rb[j]) * 0.125f);
    }
    #pragma unroll
    for (int dc = 0; dc < 4; dc++) o[st][dc] = f32x4{0.f, 0.f, 0.f, 0.f};
    #pragma unroll
    for (int r = 0; r < 4; r++){ m[st][r] = -1e30f; llp[st][r] = 0.f; }
  }

  u16* Pw = &Pl[w * 16 * 72];
  const int T = 16 - pr;

  for (int t = 0; t < T; t++){
    const int k0 = t * 64;
    __syncthreads();
    #pragma unroll
    for (int j = 0; j < 2; j++){
      int row = w * 16 + j * 8 + (lane >> 3);
      int sl = lane & 7;
      const u16* src = &qkv[(tokbase + k0 + row) * (3 * E) + E + hh * HD
                            + ((sl ^ (row & 7)) * 8)];
      gload16(src, &Kl[w * 1024 + j * 512]);
    }
    {
      int d0 = (tid & 15) * 4;
      int s  = tid >> 4;
      #pragma unroll
      for (int mh = 0; mh < 2; mh++){
        int kA = s + 32 * mh;
        const u16* vpA = &qkv[(tokbase + k0 + kA) * (3 * E) + 2 * E + hh * HD + d0];
        const u16* vpB = vpA + 16 * (3 * E);
        u16x4 va = *reinterpret_cast<const u16x4*>(vpA);
        u16x4 vb = *reinterpret_cast<const u16x4*>(vpB);
        #pragma unroll
        for (int i = 0; i < 4; i++)
          *reinterpret_cast<u32*>(&Vt[(d0 + i) * 72 + 4 * s + 2 * mh]) =
              (u32)va[i] | ((u32)vb[i] << 16);
      }
    }
    __syncthreads();

    #pragma unroll
    for (int st = 0; st < 2; st++){
      if (t > dt[st]) continue;
      const bool diag = (t == dt[st]);
      f32x4 s[4];
      #pragma unroll
      for (int kg = 0; kg < 4; kg++){
        int key = kg * 16 + l15;
        const u16* kb = &Kl[key * 64];
        bf16x8 k0f = ld_bf8(&kb[(g ^ (key & 7)) * 8]);
        bf16x8 k1f = ld_bf8(&kb[((4 + g) ^ (key & 7)) * 8]);
        f32x4 z = f32x4{0.f, 0.f, 0.f, 0.f};
        z = __builtin_amdgcn_mfma_f32_16x16x32_bf16(as_bf(q0[st]), k0f, z, 0, 0, 0);
        z = __builtin_amdgcn_mfma_f32_16x16x32_bf16(as_bf(q1[st]), k1f, z, 0, 0, 0);
        s[kg] = z;
      }
      if (diag){
        #pragma unroll
        for (int kg = 0; kg < 4; kg++){
          int key = k0 + kg * 16 + l15;
          #pragma unroll
          for (int r = 0; r < 4; r++){
            int q = qbase[st] + g * 4 + r;
            s[kg][r] = (key <= q) ? s[kg][r] : -1e9f;
          }
        }
      }
      float lmax[4];
      bool need = false;
      #pragma unroll
      for (int r = 0; r < 4; r++){
        lmax[r] = fmaxf(fmaxf(s[0][r], s[1][r]), fmaxf(s[2][r], s[3][r]));
        need = need || (lmax[r] > m[st][r] + 8.0f);
      }
      if (__any(need)){
        #pragma unroll
        for (int r = 0; r < 4; r++){
          float x = lmax[r];
          x = fmaxf(x, __shfl_xor(x, 1));
          x = fmaxf(x, __shfl_xor(x, 2));
          x = fmaxf(x, __shfl_xor(x, 4));
          x = fmaxf(x, __shfl_xor(x, 8));
          float mn = fmaxf(m[st][r], x);
          float al = __expf(m[st][r] - mn);
          m[st][r] = mn;
          llp[st][r] *= al;
          #pragma unroll
          for (int dc = 0; dc < 4; dc++) o[st][dc][r] *= al;
        }
      }
      #pragma unroll
      for (int r = 0; r < 4; r++){
        float p0 = __expf(s[0][r] - m[st][r]);
        float p1 = __expf(s[1][r] - m[st][r]);
        float p2 = __expf(s[2][r] - m[st][r]);
        float p3 = __expf(s[3][r] - m[st][r]);
        llp[st][r] += (p0 + p1) + (p2 + p3);
        u16x4 pp = { f2bf(p0), f2bf(p1), f2bf(p2), f2bf(p3) };
        *reinterpret_cast<u16x4*>(&Pw[(g * 4 + r) * 72 + 4 * l15]) = pp;
      }
      bf16x8 pa0 = ld_bf8(&Pw[l15 * 72 + g * 8]);
      bf16x8 pa1 = ld_bf8(&Pw[l15 * 72 + 32 + g * 8]);
      #pragma unroll
      for (int dc = 0; dc < 4; dc++){
        bf16x8 v0 = ld_bf8(&Vt[(dc * 16 + l15) * 72 + g * 8]);
        bf16x8 v1 = ld_bf8(&Vt[(dc * 16 + l15) * 72 + 32 + g * 8]);
        o[st][dc] = __builtin_amdgcn_mfma_f32_16x16x32_bf16(pa0, v0, o[st][dc], 0, 0, 0);
        o[st][dc] = __builtin_amdgcn_mfma_f32_16x16x32_bf16(pa1, v1, o[st][dc], 0, 0, 0);
      }
    }
  }

  #pragma unroll
  for (int st = 0; st < 2; st++){
    #pragma unroll
    for (int r = 0; r < 4; r++){
      float rs = llp[st][r];
      rs += __shfl_xor(rs, 1);
      rs += __shfl_xor(rs, 2);
      rs += __shfl_xor(rs, 4);
      rs += __shfl_xor(rs, 8);
      float inv = 1.0f / rs;
      int row = qbase[st] + g * 4 + r;
      #pragma unroll
      for (int dc = 0; dc < 4; dc++){
        int col = hh * HD + dc * 16 + l15;
        y[(tokbase + row) * E + col] = f2bf(o[st][dc][r] * inv);
      }
    }
  }
}

// ---------------- head bias pad [1000] -> [1024] f32 ----------------
__global__ __launch_bounds__(256) void biaspad_kernel(
    const float* __restrict__ hb, float* __restrict__ bpad)
{
  int i = blockIdx.x * 256 + threadIdx.x;
  if (i < 1024) bpad[i] = (i < VOC) ? hb[i] : 0.0f;
}

// ---------------- launch ----------------
extern "C" void kernel_launch(void* const* d_in, const int* in_sizes, int n_in,
                              void* d_out, int out_size, void* d_ws, size_t ws_size,
                              hipStream_t stream)
{
  const int*   idx    = (const int*)  d_in[0];
  const float* wte    = (const float*)d_in[1];
  const float* wpe    = (const float*)d_in[2];
  const float* ln1_w  = (const float*)d_in[3];
  const float* ln1_b  = (const float*)d_in[4];
  const float* qkv_w  = (const float*)d_in[5];
  const float* qkv_b  = (const float*)d_in[6];
  const float* out_w  = (const float*)d_in[7];
  const float* out_b  = (const float*)d_in[8];
  const float* ln2_w  = (const float*)d_in[9];
  const float* ln2_b  = (const float*)d_in[10];
  const float* fc1_w  = (const float*)d_in[11];
  const float* fc1_b  = (const float*)d_in[12];
  const float* fc2_w  = (const float*)d_in[13];
  const float* fc2_b  = (const float*)d_in[14];
  const float* lnf_w  = (const float*)d_in[15];
  const float* lnf_b  = (const float*)d_in[16];
  const float* head_w = (const float*)d_in[17];
  const float* head_b = (const float*)d_in[18];

  char* ws = (char*)d_ws;
  float* x    = (float*)(ws + 0);            // 4096x1024 f32   16777216
  u16*   h    = (u16*)  (ws + 16777216);     // 4096x1024 bf16   8388608
  u16*   qkvb = (u16*)  (ws + 25165824);     // 4096x3072 bf16  25165824
  u16*   y    = (u16*)  (ws + 50331648);     // 4096x1024 bf16   8388608
  u16*   g    = (u16*)  (ws + 58720256);     // 4096x4096 bf16  33554432
  u16*   wq   = (u16*)  (ws + 92274688);     // 3072x1024 bf16   6291456
  u16*   wo   = (u16*)  (ws + 98566144);     // 1024x1024 bf16   2097152
  u16*   w1   = (u16*)  (ws + 100663296);    // 4096x1024 bf16   8388608
  u16*   w2   = (u16*)  (ws + 109051904);    // 1024x4096 bf16   8388608
  u16*   wh   = (u16*)  (ws + 117440512);    // 1024x1024 bf16   2097152
  float* hbp  = (float*)(ws + 119537664);    // 1024 f32            4096
  u16*   p    = (u16*)  (ws + 119541760);    // 4096x1024 bf16   8388608
  // total: 127930368 bytes (~122 MiB)

  constexpr int LDS_QKV = 4 * (448 * 32) * 2;     // 114688 bytes (BM256/BN192)
  constexpr int LDS_BIG = 4 * (512 * 32) * 2;     // 131072 bytes (BM256/BN256)
  constexpr int LDS_SML = 4 * (192 * 32) * 2;     // 49152 bytes (BM128/BN64)
  hipFuncSetAttribute((const void*)gemm2_kernel<EPI_BF16, 8, 4, 8, 3, 2>,
                      hipFuncAttributeMaxDynamicSharedMemorySize, LDS_QKV);
  hipFuncSetAttribute((const void*)gemm2_kernel<EPI_GELU, 8, 4, 8, 4, 2>,
                      hipFuncAttributeMaxDynamicSharedMemorySize, LDS_BIG);
  hipFuncSetAttribute((const void*)gemm2_kernel<EPI_BF16, 4, 2, 4, 2, 2>,
                      hipFuncAttributeMaxDynamicSharedMemorySize, LDS_SML);
  hipFuncSetAttribute((const void*)gemm2_kernel<EPI_OUT, 4, 2, 4, 2, 2>,
                      hipFuncAttributeMaxDynamicSharedMemorySize, LDS_SML);

  embed_kernel<<<MTOK, 256, 0, stream>>>(idx, wte, wpe, x);
  biaspad_kernel<<<4, 256, 0, stream>>>(head_b, hbp);

  for (int l = 0; l < NL; l++){
    if (l == 0){
      ln_kernel<<<MTOK, 256, 0, stream>>>(x, ln1_w, ln1_b, h);
    } else {
      // fused: x += p (prev layer fc2 output) ; h = LN1(x)
      lnadd_kernel<<<MTOK, 256, 0, stream>>>(x, p, ln1_w + l * E, ln1_b + l * E, h);
    }
    wconv4_kernel<<<3072, 256, 0, stream>>>(
        qkv_w + (size_t)l * E * 3 * E, out_w + (size_t)l * E * E,
        fc1_w + (size_t)l * E * HID, fc2_w + (size_t)l * HID * E,
        wq, nullptr, w1, w2, wo);
    gemm2_kernel<EPI_BF16, 8, 4, 8, 3, 2><<<dim3(16, 16), 512, LDS_QKV, stream>>>(
        h, wq, qkv_b + (size_t)l * 3 * E, qkvb, MTOK, 3 * E, E);
    attn_kernel<<<dim3(8, NH, NB), 256, 0, stream>>>(qkvb, y);
    // out-proj: raw output (bf16) -> p; residual-add fused into next lnadd
    gemm2_kernel<EPI_BF16, 4, 2, 4, 2, 2><<<dim3(16, 32), 256, LDS_SML, stream>>>(
        y, wo, out_b + (size_t)l * E, p, MTOK, E, E);
    lnadd_kernel<<<MTOK, 256, 0, stream>>>(x, p, ln2_w + l * E, ln2_b + l * E, h);
    gemm2_kernel<EPI_GELU, 8, 4, 8, 4, 2><<<dim3(16, 16), 512, LDS_BIG, stream>>>(
        h, w1, fc1_b + (size_t)l * HID, g, MTOK, HID, E);
    // fc2: raw output (bf16) -> p; residual-add fused into next lnadd / lnf
    gemm2_kernel<EPI_BF16, 4, 2, 4, 2, 2><<<dim3(16, 32), 256, LDS_SML, stream>>>(
        g, w2, fc2_b + (size_t)l * E, p, MTOK, E, HID);
  }
  lnadd_kernel<<<MTOK, 256, 0, stream>>>(x, p, lnf_w, lnf_b, h);
  wconv_kernel<<<dim3(16, 16), 256, 0, stream>>>(head_w, wh, E, VOC, E);
  gemm2_kernel<EPI_OUT, 4, 2, 4, 2, 2><<<dim3(16, 32), 256, LDS_SML, stream>>>(
      h, wh, hbp, (float*)d_out, MTOK, E, E);
}

// Round 18
// 1777.100 us; speedup vs baseline: 1.1190x; 1.0233x over previous
//
#include <hip/hip_runtime.h>
#include <math.h>

// GPT fwd: B=4, S=1024, L=8, H=16, E=1024, D=64, HID=4096, V=1000
// Workspace requirement: ~114 MB (see offsets below).

typedef unsigned short u16;
typedef unsigned int u32;
typedef __attribute__((ext_vector_type(4))) float f32x4;
typedef __attribute__((ext_vector_type(8))) __bf16 bf16x8;
typedef __attribute__((ext_vector_type(8))) u16 u16x8;
typedef __attribute__((ext_vector_type(4))) u16 u16x4;

#define E 1024
#define HID 4096
#define NH 16
#define HD 64
#define SEQ 1024
#define NB 4
#define NL 8
#define MTOK 4096
#define VOC 1000

#define VMCNT(n) asm volatile("s_waitcnt vmcnt(" #n ")" ::: "memory")

__device__ __forceinline__ u16 f2bf(float f){
  u32 u = __float_as_uint(f);
  u32 r = (u + 0x7fffu + ((u >> 16) & 1u)) >> 16;
  return (u16)r;
}
__device__ __forceinline__ float bf2f(u16 b){
  return __uint_as_float((u32)b << 16);
}
__device__ __forceinline__ bf16x8 ld_bf8(const u16* p){
  return *reinterpret_cast<const bf16x8*>(p);
}
__device__ __forceinline__ bf16x8 as_bf(u16x8 v){
  return __builtin_bit_cast(bf16x8, v);
}

// async global->LDS, 16B per lane; LDS dest = wave-uniform base + lane*16 (HW)
__device__ __forceinline__ void gload16(const void* g, void* l){
  __builtin_amdgcn_global_load_lds(
      (const __attribute__((address_space(1))) void*)g,
      (__attribute__((address_space(3))) void*)l, 16, 0, 0);
}

// ---------------- embed: x = bf16(wte[idx] + wpe[s]) ----------------
__global__ __launch_bounds__(256) void embed_kernel(
    const int* __restrict__ idx, const float* __restrict__ wte,
    const float* __restrict__ wpe, u16* __restrict__ x)
{
  int tok = blockIdx.x, tid = threadIdx.x;
  int id = idx[tok];
  int s = tok & (SEQ - 1);
  f32x4 a = *reinterpret_cast<const f32x4*>(&wte[(size_t)id * E + tid * 4]);
  f32x4 p = *reinterpret_cast<const f32x4*>(&wpe[(size_t)s * E + tid * 4]);
  u16x4 r;
  #pragma unroll
  for (int j = 0; j < 4; j++) r[j] = f2bf(a[j] + p[j]);
  *reinterpret_cast<u16x4*>(&x[(size_t)tok * E + tid * 4]) = r;
}

// ---------------- layernorm: h = LN(x)*w + b (bf16 x, bf16 out) ----------------
__global__ __launch_bounds__(256) void ln_kernel(
    const u16* __restrict__ x, const float* __restrict__ w,
    const float* __restrict__ b, u16* __restrict__ h)
{
  int row = blockIdx.x, tid = threadIdx.x;
  u16x4 xv = *reinterpret_cast<const u16x4*>(&x[(size_t)row * E + tid * 4]);
  f32x4 v;
  #pragma unroll
  for (int j = 0; j < 4; j++) v[j] = bf2f(xv[j]);
  float s = v[0] + v[1] + v[2] + v[3];
  float q = v[0]*v[0] + v[1]*v[1] + v[2]*v[2] + v[3]*v[3];
  #pragma unroll
  for (int mm = 1; mm < 64; mm <<= 1){
    s += __shfl_xor(s, mm);
    q += __shfl_xor(q, mm);
  }
  __shared__ float red[8];
  int wv = tid >> 6;
  if ((tid & 63) == 0){ red[wv] = s; red[4 + wv] = q; }
  __syncthreads();
  s = red[0] + red[1] + red[2] + red[3];
  q = red[4] + red[5] + red[6] + red[7];
  float mean = s * (1.0f / E);
  float var = q * (1.0f / E) - mean * mean;
  float rstd = rsqrtf(var + 1e-5f);
  f32x4 wv4 = *reinterpret_cast<const f32x4*>(w + tid * 4);
  f32x4 bv4 = *reinterpret_cast<const f32x4*>(b + tid * 4);
  u16x4 o;
  #pragma unroll
  for (int j = 0; j < 4; j++)
    o[j] = f2bf((v[j] - mean) * rstd * wv4[j] + bv4[j]);
  *reinterpret_cast<u16x4*>(&h[(size_t)row * E + tid * 4]) = o;
}

// ---- fused residual+LN: v = x + p (f32); x = bf16(v); h = LN(v)*w + b ----
__global__ __launch_bounds__(256) void lnadd_kernel(
    u16* __restrict__ x, const u16* __restrict__ p,
    const float* __restrict__ w, const float* __restrict__ b,
    u16* __restrict__ h)
{
  int row = blockIdx.x, tid = threadIdx.x;
  u16* xr = x + (size_t)row * E + tid * 4;
  u16x4 xv = *reinterpret_cast<const u16x4*>(xr);
  u16x4 pv = *reinterpret_cast<const u16x4*>(&p[(size_t)row * E + tid * 4]);
  f32x4 v;
  u16x4 nx;
  #pragma unroll
  for (int j = 0; j < 4; j++){
    v[j] = bf2f(xv[j]) + bf2f(pv[j]);
    nx[j] = f2bf(v[j]);
  }
  *reinterpret_cast<u16x4*>(xr) = nx;
  float s = v[0] + v[1] + v[2] + v[3];
  float q = v[0]*v[0] + v[1]*v[1] + v[2]*v[2] + v[3]*v[3];
  #pragma unroll
  for (int mm = 1; mm < 64; mm <<= 1){
    s += __shfl_xor(s, mm);
    q += __shfl_xor(q, mm);
  }
  __shared__ float red[8];
  int wv = tid >> 6;
  if ((tid & 63) == 0){ red[wv] = s; red[4 + wv] = q; }
  __syncthreads();
  s = red[0] + red[1] + red[2] + red[3];
  q = red[4] + red[5] + red[6] + red[7];
  float mean = s * (1.0f / E);
  float var = q * (1.0f / E) - mean * mean;
  float rstd = rsqrtf(var + 1e-5f);
  f32x4 wv4 = *reinterpret_cast<const f32x4*>(w + tid * 4);
  f32x4 bv4 = *reinterpret_cast<const f32x4*>(b + tid * 4);
  u16x4 o;
  #pragma unroll
  for (int j = 0; j < 4; j++)
    o[j] = f2bf((v[j] - mean) * rstd * wv4[j] + bv4[j]);
  *reinterpret_cast<u16x4*>(&h[(size_t)row * E + tid * 4]) = o;
}

// ------- merged per-layer weight convert+transpose (all Nsrc % 64 == 0) -------
__global__ __launch_bounds__(256) void wconv4_kernel(
    const float* __restrict__ qw, const float* __restrict__ ow,
    const float* __restrict__ f1, const float* __restrict__ f2,
    u16* __restrict__ dq, u16* __restrict__ d_unused, u16* __restrict__ d1,
    u16* __restrict__ d2, u16* __restrict__ dw_out)
{
  const int bid = blockIdx.x, tid = threadIdx.x;
  const float* W; u16* Wt; int K, Nsrc, nx, base;
  if (bid < 768)      { W = qw; Wt = dq;     K = 1024; Nsrc = 3072; nx = 48; base = 0; }
  else if (bid < 1024){ W = ow; Wt = dw_out; K = 1024; Nsrc = 1024; nx = 16; base = 768; }
  else if (bid < 2048){ W = f1; Wt = d1;     K = 1024; Nsrc = 4096; nx = 64; base = 1024; }
  else                { W = f2; Wt = d2;     K = 4096; Nsrc = 1024; nx = 16; base = 2048; }
  const int t = bid - base;
  const int n0 = (t % nx) * 64, k0 = (t / nx) * 64;

  __shared__ float T[64][65];
  const int c = (tid & 15) * 4, rbase = tid >> 4;
  #pragma unroll
  for (int p = 0; p < 4; p++){
    int r = rbase + p * 16;
    f32x4 v = *reinterpret_cast<const f32x4*>(&W[(size_t)(k0 + r) * Nsrc + n0 + c]);
    T[r][c] = v[0]; T[r][c+1] = v[1]; T[r][c+2] = v[2]; T[r][c+3] = v[3];
  }
  __syncthreads();
  const int nr = tid >> 2, ks = (tid & 3) * 16;
  u16x8 o0, o1;
  #pragma unroll
  for (int i = 0; i < 8; i++){
    o0[i] = f2bf(T[ks + i][nr]);
    o1[i] = f2bf(T[ks + 8 + i][nr]);
  }
  u16* dst = &Wt[(size_t)(n0 + nr) * K + k0 + ks];
  *reinterpret_cast<u16x8*>(dst) = o0;
  *reinterpret_cast<u16x8*>(dst + 8) = o1;
}

// ------- single weight convert+transpose (head: Nsrc=1000 padded to 1024) -----
__global__ __launch_bounds__(256) void wconv_kernel(
    const float* __restrict__ W, u16* __restrict__ Wt,
    int K, int Nsrc, int N)
{
  __shared__ float T[64][65];
  const int tid = threadIdx.x;
  const int n0 = blockIdx.x * 64, k0 = blockIdx.y * 64;
  const int c = (tid & 15) * 4, rbase = tid >> 4;
  #pragma unroll
  for (int p = 0; p < 4; p++){
    int r = rbase + p * 16;
    #pragma unroll
    for (int j = 0; j < 4; j++){
      int n = n0 + c + j;
      T[r][c + j] = (n < Nsrc) ? W[(size_t)(k0 + r) * Nsrc + n] : 0.0f;
    }
  }
  __syncthreads();
  const int nr = tid >> 2, ks = (tid & 3) * 16;
  u16x8 o0, o1;
  #pragma unroll
  for (int i = 0; i < 8; i++){
    o0[i] = f2bf(T[ks + i][nr]);
    o1[i] = f2bf(T[ks + 8 + i][nr]);
  }
  u16* dst = &Wt[(size_t)(n0 + nr) * K + k0 + ks];
  *reinterpret_cast<u16x8*>(dst) = o0;
  *reinterpret_cast<u16x8*>(dst + 8) = o1;
}

// ---------------- GEMM: C = A(bf16)[M,K] @ Wt(bf16)[N,K]^T + bias ----------------
// NS=4 ring, BK=32, phase split (r13):
//   [ds_read frags(c) -> counted VMCNT -> s_barrier -> setprio+MFMA(c) -> STAGE(c+3)]
// Uniform staging RPW in {3,4}; non-uniform (BM=256/BN=192): waves 0-3 stage 4 A,
// waves 4-7 stage 3 B; counted vmcnt uses the wave's own loads-per-chunk.
// T1 XCD swizzle, T2 16B-slot XOR swizzle, T5 setprio.
enum { EPI_BF16 = 0, EPI_GELU = 1, EPI_OUT = 3 };

template<int EPI, int NW, int NWX, int FM, int FN, int MINW>
__global__ __launch_bounds__(NW * 64, MINW) void gemm2_kernel(
    const u16* __restrict__ A, const u16* __restrict__ Wt,
    const float* __restrict__ bias, void* __restrict__ outp,
    int M, int N, int K)
{
  constexpr int BM = FM * 16 * (NW / NWX);
  constexpr int BN = FN * 16 * NWX;
  constexpr int SLOT = (BM + BN) * 32;       // u16 per slot (A | B), BK=32
  constexpr int GROUPS = (BM + BN) / 16;
  constexpr bool UNI = (GROUPS % NW) == 0;
  constexpr int RPW = UNI ? GROUPS / NW : 0; // uniform groups per wave
  constexpr int NS = 4;
  extern __shared__ u16 lds[];               // NS * SLOT * 2 bytes

  const int tid = threadIdx.x;
  const int lane = tid & 63, w = tid >> 6;
  const int l15 = lane & 15, g = lane >> 4;
  const int wr = w / NWX, wc = w % NWX;
  const int wrbase = wr * FM * 16, wcbase = wc * FN * 16;

  // T1: bijective XCD swizzle (all grids have nwg % 8 == 0)
  const int nwgx = gridDim.x;
  const int bid = blockIdx.y * nwgx + blockIdx.x;
  const int cpx = (nwgx * gridDim.y) >> 3;
  const int swz = (bid & 7) * cpx + (bid >> 3);
  const int bm = (swz / nwgx) * BM, bn = (swz % nwgx) * BN;

  const u16* Abase = A + (size_t)bm * K;
  const u16* Bbase = Wt + (size_t)bn * K;

  f32x4 acc[FM][FN];
  #pragma unroll
  for (int i = 0; i < FM; i++)
    #pragma unroll
    for (int j = 0; j < FN; j++)
      acc[i][j] = f32x4{0.f, 0.f, 0.f, 0.f};

  // stage chunk cc into slot s. LDS linear [row][32k]; source 16B-slot pre-swizzled.
  const int lr = lane >> 2, ps = lane & 3;
  const int ss = ps ^ ((lane >> 4) & 3);     // (row>>2)&3 == (lane>>4)&3 (base%16==0)
  auto STAGE = [&](int s, int cc){
    const int k0 = cc * 32;
    u16* As = lds + s * SLOT;
    u16* Bs = As + BM * 32;
    if constexpr (UNI){
      #pragma unroll
      for (int j = 0; j < RPW; j++){
        int base = (w * RPW + j) * 16;
        if (base < BM){
          gload16(&Abase[(size_t)(base + lr) * K + k0 + ss * 8], As + base * 32);
        } else {
          int rb = base - BM;
          gload16(&Bbase[(size_t)(rb + lr) * K + k0 + ss * 8], Bs + rb * 32);
        }
      }
    } else {
      // BM=256 (16 A-groups), BN=192 (12 B-groups): w<4 -> 4 A; w>=4 -> 3 B
      static_assert(BM == 256 && BN == 192, "non-uniform path is specialized");
      if (w < 4){
        #pragma unroll
        for (int j = 0; j < 4; j++){
          int base = (w * 4 + j) * 16;
          gload16(&Abase[(size_t)(base + lr) * K + k0 + ss * 8], As + base * 32);
        }
      } else {
        #pragma unroll
        for (int j = 0; j < 3; j++){
          int rb = ((w - 4) * 3 + j) * 16;
          gload16(&Bbase[(size_t)(rb + lr) * K + k0 + ss * 8], Bs + rb * 32);
        }
      }
    }
  };
  // counted wait: allow the newest chunk's loads (this wave's count) to stay in flight
  auto WAIT1 = [&](){
    if constexpr (UNI){
      static_assert(!UNI || RPW == 4 || RPW == 3, "vmcnt literal covers RPW 3/4");
      if constexpr (RPW == 4) { VMCNT(4); } else { VMCNT(3); }
    } else {
      if (w < 4) { VMCNT(4); } else { VMCNT(3); }
    }
  };

  const int nt = K >> 5;                     // >= 32 for all our shapes
  STAGE(0, 0); STAGE(1, 1); STAGE(2, 2);
  WAIT1();                                   // chunks 0,1 landed (chunk 2 in flight)
  __builtin_amdgcn_sched_barrier(0);
  __builtin_amdgcn_s_barrier();
  __builtin_amdgcn_sched_barrier(0);

  int sl = 0;
  for (int c = 0; c < nt; c++){
    // ---- ds_read frags of chunk c (visible since previous barrier) ----
    const u16* As = lds + sl * SLOT;
    const u16* Bs = As + BM * 32;
    bf16x8 af[FM], bf[FN];
    const int rsw = (g ^ (l15 >> 2)) * 8;    // swizzled 16B slot on read
    #pragma unroll
    for (int mf = 0; mf < FM; mf++)
      af[mf] = ld_bf8(&As[(wrbase + mf * 16 + l15) * 32 + rsw]);
    #pragma unroll
    for (int nf = 0; nf < FN; nf++)
      bf[nf] = ld_bf8(&Bs[(wcbase + nf * 16 + l15) * 32 + rsw]);
    __builtin_amdgcn_sched_barrier(0);
    // ---- counted vmcnt: chunk c+1 landed before the barrier releases ----
    if (c + 2 <= nt - 1) { WAIT1(); } else { VMCNT(0); }
    __builtin_amdgcn_sched_barrier(0);
    __builtin_amdgcn_s_barrier();            // chunk c+1 visible; reads of c issued
    __builtin_amdgcn_sched_barrier(0);
    // ---- MFMA ----
    __builtin_amdgcn_s_setprio(1);
    #pragma unroll
    for (int mf = 0; mf < FM; mf++)
      #pragma unroll
      for (int nf = 0; nf < FN; nf++)
        acc[mf][nf] = __builtin_amdgcn_mfma_f32_16x16x32_bf16(
            af[mf], bf[nf], acc[mf][nf], 0, 0, 0);
    __builtin_amdgcn_s_setprio(0);
    // ---- prefetch chunk c+3 into slot (c-1)%4 (dead once waves passed barrier(c)) ----
    if (c + 3 < nt){
      int s2 = sl + 3; if (s2 >= NS) s2 -= NS;
      STAGE(s2, c + 3);
    }
    sl++; if (sl >= NS) sl -= NS;
  }

  // epilogue (C/D: col = lane&15, row = (lane>>4)*4 + reg)
  #pragma unroll
  for (int mf = 0; mf < FM; mf++){
    #pragma unroll
    for (int nf = 0; nf < FN; nf++){
      int col = bn + wcbase + nf * 16 + l15;
      float bv = bias[col];
      #pragma unroll
      for (int r = 0; r < 4; r++){
        int row = bm + wrbase + mf * 16 + g * 4 + r;
        float v = acc[mf][nf][r] + bv;
        if constexpr (EPI == EPI_BF16){
          ((u16*)outp)[(size_t)row * N + col] = f2bf(v);
        } else if constexpr (EPI == EPI_GELU){
          ((u16*)outp)[(size_t)row * N + col] =
              f2bf(0.5f * v * (1.0f + erff(v * 0.70710678118654752f)));
        } else {
          if (col < VOC)
            ((float*)outp)[(size_t)row * VOC + col] = v;
        }
      }
    }
  }
}

// ---------------- flash attention (causal), paired 64-row q-blocks ----------------
__global__ __launch_bounds__(256) void attn_kernel(
    const u16* __restrict__ qkv, u16* __restrict__ y)
{
  __shared__ u16 Kl[64 * 64];       // [key][dslot swizzled], 8KB
  __shared__ u16 Vt[64 * 72];       // [d][c'], stride 72, 9KB
  __shared__ u16 Pl[4 * 16 * 72];   // per-wave [q][c'], 9KB
  const int pr = blockIdx.x, hh = blockIdx.y, b = blockIdx.z;
  const int tid = threadIdx.x;
  const int lane = tid & 63, w = tid >> 6;
  const int l15 = lane & 15, g = lane >> 4;
  const size_t tokbase = (size_t)b * SEQ;
  const int qstart[2] = { pr * 64, (15 - pr) * 64 };

  int qbase[2], dt[2];
  u16x8 q0[2], q1[2];
  f32x4 o[2][4];
  float m[2][4], llp[2][4];
  #pragma unroll
  for (int st = 0; st < 2; st++){
    qbase[st] = qstart[st] + w * 16;
    dt[st] = qbase[st] >> 6;
    const u16* qp = &qkv[(tokbase + qbase[st] + l15) * (3 * E) + hh * HD];
    u16x8 ra = *reinterpret_cast<const u16x8*>(&qp[g * 8]);
    u16x8 rb = *reinterpret_cast<const u16x8*>(&qp[32 + g * 8]);
    #pragma unroll
    for (int j = 0; j < 8; j++){
      q0[st][j] = f2bf(bf2f(ra[j]) * 0.125f);
      q1[st][j] = f2bf(bf2f(rb[j]) * 0.125f);
    }
    #pragma unroll
    for (int dc = 0; dc < 4; dc++) o[st][dc] = f32x4{0.f, 0.f, 0.f, 0.f};
    #pragma unroll
    for (int r = 0; r < 4; r++){ m[st][r] = -1e30f; llp[st][r] = 0.f; }
  }

  u16* Pw = &Pl[w * 16 * 72];
  const int T = 16 - pr;

  for (int t = 0; t < T; t++){
    const int k0 = t * 64;
    __syncthreads();
    #pragma unroll
    for (int j = 0; j < 2; j++){
      int row = w * 16 + j * 8 + (lane >> 3);
      int sl = lane & 7;
      const u16* src = &qkv[(tokbase + k0 + row) * (3 * E) + E + hh * HD
                            + ((sl ^ (row & 7)) * 8)];
      gload16(src, &Kl[w * 1024 + j * 512]);
    }
    {
      int d0 = (tid & 15) * 4;
      int s  = tid >> 4;
      #pragma unroll
      for (int mh = 0; mh < 2; mh++){
        int kA = s + 32 * mh;
        const u16* vpA = &qkv[(tokbase + k0 + kA) * (3 * E) + 2 * E + hh * HD + d0];
        const u16* vpB = vpA + 16 * (3 * E);
        u16x4 va = *reinterpret_cast<const u16x4*>(vpA);
        u16x4 vb = *reinterpret_cast<const u16x4*>(vpB);
        #pragma unroll
        for (int i = 0; i < 4; i++)
          *reinterpret_cast<u32*>(&Vt[(d0 + i) * 72 + 4 * s + 2 * mh]) =
              (u32)va[i] | ((u32)vb[i] << 16);
      }
    }
    __syncthreads();

    #pragma unroll
    for (int st = 0; st < 2; st++){
      if (t > dt[st]) continue;
      const bool diag = (t == dt[st]);
      f32x4 s[4];
      #pragma unroll
      for (int kg = 0; kg < 4; kg++){
        int key = kg * 16 + l15;
        const u16* kb = &Kl[key * 64];
        bf16x8 k0f = ld_bf8(&kb[(g ^ (key & 7)) * 8]);
        bf16x8 k1f = ld_bf8(&kb[((4 + g) ^ (key & 7)) * 8]);
        f32x4 z = f32x4{0.f, 0.f, 0.f, 0.f};
        z = __builtin_amdgcn_mfma_f32_16x16x32_bf16(as_bf(q0[st]), k0f, z, 0, 0, 0);
        z = __builtin_amdgcn_mfma_f32_16x16x32_bf16(as_bf(q1[st]), k1f, z, 0, 0, 0);
        s[kg] = z;
      }
      if (diag){
        #pragma unroll
        for (int kg = 0; kg < 4; kg++){
          int key = k0 + kg * 16 + l15;
          #pragma unroll
          for (int r = 0; r < 4; r++){
            int q = qbase[st] + g * 4 + r;
            s[kg][r] = (key <= q) ? s[kg][r] : -1e9f;
          }
        }
      }
      float lmax[4];
      bool need = false;
      #pragma unroll
      for (int r = 0; r < 4; r++){
        lmax[r] = fmaxf(fmaxf(s[0][r], s[1][r]), fmaxf(s[2][r], s[3][r]));
        need = need || (lmax[r] > m[st][r] + 8.0f);
      }
      if (__any(need)){
        #pragma unroll
        for (int r = 0; r < 4; r++){
          float x = lmax[r];
          x = fmaxf(x, __shfl_xor(x, 1));
          x = fmaxf(x, __shfl_xor(x, 2));
          x = fmaxf(x, __shfl_xor(x, 4));
          x = fmaxf(x, __shfl_xor(x, 8));
          float mn = fmaxf(m[st][r], x);
          float al = __expf(m[st][r] - mn);
          m[st][r] = mn;
          llp[st][r] *= al;
          #pragma unroll
          for (int dc = 0; dc < 4; dc++) o[st][dc][r] *= al;
        }
      }
      #pragma unroll
      for (int r = 0; r < 4; r++){
        float p0 = __expf(s[0][r] - m[st][r]);
        float p1 = __expf(s[1][r] - m[st][r]);
        float p2 = __expf(s[2][r] - m[st][r]);
        float p3 = __expf(s[3][r] - m[st][r]);
        llp[st][r] += (p0 + p1) + (p2 + p3);
        u16x4 pp = { f2bf(p0), f2bf(p1), f2bf(p2), f2bf(p3) };
        *reinterpret_cast<u16x4*>(&Pw[(g * 4 + r) * 72 + 4 * l15]) = pp;
      }
      bf16x8 pa0 = ld_bf8(&Pw[l15 * 72 + g * 8]);
      bf16x8 pa1 = ld_bf8(&Pw[l15 * 72 + 32 + g * 8]);
      #pragma unroll
      for (int dc = 0; dc < 4; dc++){
        bf16x8 v0 = ld_bf8(&Vt[(dc * 16 + l15) * 72 + g * 8]);
        bf16x8 v1 = ld_bf8(&Vt[(dc * 16 + l15) * 72 + 32 + g * 8]);
        o[st][dc] = __builtin_amdgcn_mfma_f32_16x16x32_bf16(pa0, v0, o[st][dc], 0, 0, 0);
        o[st][dc] = __builtin_amdgcn_mfma_f32_16x16x32_bf16(pa1, v1, o[st][dc], 0, 0, 0);
      }
    }
  }

  #pragma unroll
  for (int st = 0; st < 2; st++){
    #pragma unroll
    for (int r = 0; r < 4; r++){
      float rs = llp[st][r];
      rs += __shfl_xor(rs, 1);
      rs += __shfl_xor(rs, 2);
      rs += __shfl_xor(rs, 4);
      rs += __shfl_xor(rs, 8);
      float inv = 1.0f / rs;
      int row = qbase[st] + g * 4 + r;
      #pragma unroll
      for (int dc = 0; dc < 4; dc++){
        int col = hh * HD + dc * 16 + l15;
        y[(tokbase + row) * E + col] = f2bf(o[st][dc][r] * inv);
      }
    }
  }
}

// ---------------- head bias pad [1000] -> [1024] f32 ----------------
__global__ __launch_bounds__(256) void biaspad_kernel(
    const float* __restrict__ hb, float* __restrict__ bpad)
{
  int i = blockIdx.x * 256 + threadIdx.x;
  if (i < 1024) bpad[i] = (i < VOC) ? hb[i] : 0.0f;
}

// ---------------- launch ----------------
extern "C" void kernel_launch(void* const* d_in, const int* in_sizes, int n_in,
                              void* d_out, int out_size, void* d_ws, size_t ws_size,
                              hipStream_t stream)
{
  const int*   idx    = (const int*)  d_in[0];
  const float* wte    = (const float*)d_in[1];
  const float* wpe    = (const float*)d_in[2];
  const float* ln1_w  = (const float*)d_in[3];
  const float* ln1_b  = (const float*)d_in[4];
  const float* qkv_w  = (const float*)d_in[5];
  const float* qkv_b  = (const float*)d_in[6];
  const float* out_w  = (const float*)d_in[7];
  const float* out_b  = (const float*)d_in[8];
  const float* ln2_w  = (const float*)d_in[9];
  const float* ln2_b  = (const float*)d_in[10];
  const float* fc1_w  = (const float*)d_in[11];
  const float* fc1_b  = (const float*)d_in[12];
  const float* fc2_w  = (const float*)d_in[13];
  const float* fc2_b  = (const float*)d_in[14];
  const float* lnf_w  = (const float*)d_in[15];
  const float* lnf_b  = (const float*)d_in[16];
  const float* head_w = (const float*)d_in[17];
  const float* head_b = (const float*)d_in[18];

  char* ws = (char*)d_ws;
  u16*   x    = (u16*)  (ws + 0);            // 4096x1024 bf16   8388608
  u16*   h    = (u16*)  (ws + 8388608);      // 4096x1024 bf16   8388608
  u16*   qkvb = (u16*)  (ws + 16777216);     // 4096x3072 bf16  25165824
  u16*   y    = (u16*)  (ws + 41943040);     // 4096x1024 bf16   8388608
  u16*   g    = (u16*)  (ws + 50331648);     // 4096x4096 bf16  33554432
  u16*   wq   = (u16*)  (ws + 83886080);     // 3072x1024 bf16   6291456
  u16*   wo   = (u16*)  (ws + 90177536);     // 1024x1024 bf16   2097152
  u16*   w1   = (u16*)  (ws + 92274688);     // 4096x1024 bf16   8388608
  u16*   w2   = (u16*)  (ws + 100663296);    // 1024x4096 bf16   8388608
  u16*   wh   = (u16*)  (ws + 109051904);    // 1024x1024 bf16   2097152
  float* hbp  = (float*)(ws + 111149056);    // 1024 f32            4096
  u16*   p    = (u16*)  (ws + 111153152);    // 4096x1024 bf16   8388608
  // total: 119541760 bytes (~114 MiB)

  constexpr int LDS_QKV = 4 * (448 * 32) * 2;     // 114688 bytes (BM256/BN192)
  constexpr int LDS_BIG = 4 * (512 * 32) * 2;     // 131072 bytes (BM256/BN256)
  constexpr int LDS_SML = 4 * (192 * 32) * 2;     // 49152 bytes (BM128/BN64)
  hipFuncSetAttribute((const void*)gemm2_kernel<EPI_BF16, 8, 4, 8, 3, 2>,
                      hipFuncAttributeMaxDynamicSharedMemorySize, LDS_QKV);
  hipFuncSetAttribute((const void*)gemm2_kernel<EPI_GELU, 8, 4, 8, 4, 2>,
                      hipFuncAttributeMaxDynamicSharedMemorySize, LDS_BIG);
  hipFuncSetAttribute((const void*)gemm2_kernel<EPI_BF16, 4, 2, 4, 2, 2>,
                      hipFuncAttributeMaxDynamicSharedMemorySize, LDS_SML);
  hipFuncSetAttribute((const void*)gemm2_kernel<EPI_OUT, 4, 2, 4, 2, 2>,
                      hipFuncAttributeMaxDynamicSharedMemorySize, LDS_SML);

  embed_kernel<<<MTOK, 256, 0, stream>>>(idx, wte, wpe, x);
  biaspad_kernel<<<4, 256, 0, stream>>>(head_b, hbp);

  for (int l = 0; l < NL; l++){
    if (l == 0){
      ln_kernel<<<MTOK, 256, 0, stream>>>(x, ln1_w, ln1_b, h);
    } else {
      lnadd_kernel<<<MTOK, 256, 0, stream>>>(x, p, ln1_w + l * E, ln1_b + l * E, h);
    }
    wconv4_kernel<<<3072, 256, 0, stream>>>(
        qkv_w + (size_t)l * E * 3 * E, out_w + (size_t)l * E * E,
        fc1_w + (size_t)l * E * HID, fc2_w + (size_t)l * HID * E,
        wq, nullptr, w1, w2, wo);
    gemm2_kernel<EPI_BF16, 8, 4, 8, 3, 2><<<dim3(16, 16), 512, LDS_QKV, stream>>>(
        h, wq, qkv_b + (size_t)l * 3 * E, qkvb, MTOK, 3 * E, E);
    attn_kernel<<<dim3(8, NH, NB), 256, 0, stream>>>(qkvb, y);
    gemm2_kernel<EPI_BF16, 4, 2, 4, 2, 2><<<dim3(16, 32), 256, LDS_SML, stream>>>(
        y, wo, out_b + (size_t)l * E, p, MTOK, E, E);
    lnadd_kernel<<<MTOK, 256, 0, stream>>>(x, p, ln2_w + l * E, ln2_b + l * E, h);
    gemm2_kernel<EPI_GELU, 8, 4, 8, 4, 2><<<dim3(16, 16), 512, LDS_BIG, stream>>>(
        h, w1, fc1_b + (size_t)l * HID, g, MTOK, HID, E);
    gemm2_kernel<EPI_BF16, 4, 2, 4, 2, 2><<<dim3(16, 32), 256, LDS_SML, stream>>>(
        g, w2, fc2_b + (size_t)l * E, p, MTOK, E, HID);
  }
  lnadd_kernel<<<MTOK, 256, 0, stream>>>(x, p, lnf_w, lnf_b, h);
  wconv_kernel<<<dim3(16, 16), 256, 0, stream>>>(head_w, wh, E, VOC, E);
  gemm2_kernel<EPI_OUT, 4, 2, 4, 2, 2><<<dim3(16, 32), 256, LDS_SML, stream>>>(
      h, wh, hbp, (float*)d_out, MTOK, E, E);
}

// Round 19
// 1770.670 us; speedup vs baseline: 1.1230x; 1.0036x over previous
//
#include <hip/hip_runtime.h>
#include <math.h>

// GPT fwd: B=4, S=1024, L=8, H=16, E=1024, D=64, HID=4096, V=1000
// Workspace requirement: ~114 MB (see offsets below).

typedef unsigned short u16;
typedef unsigned int u32;
typedef __attribute__((ext_vector_type(4))) float f32x4;
typedef __attribute__((ext_vector_type(8))) __bf16 bf16x8;
typedef __attribute__((ext_vector_type(8))) u16 u16x8;
typedef __attribute__((ext_vector_type(4))) u16 u16x4;

#define E 1024
#define HID 4096
#define NH 16
#define HD 64
#define SEQ 1024
#define NB 4
#define NL 8
#define MTOK 4096
#define VOC 1000

#define VMCNT(n) asm volatile("s_waitcnt vmcnt(" #n ")" ::: "memory")

__device__ __forceinline__ u16 f2bf(float f){
  u32 u = __float_as_uint(f);
  u32 r = (u + 0x7fffu + ((u >> 16) & 1u)) >> 16;
  return (u16)r;
}
__device__ __forceinline__ float bf2f(u16 b){
  return __uint_as_float((u32)b << 16);
}
__device__ __forceinline__ bf16x8 ld_bf8(const u16* p){
  return *reinterpret_cast<const bf16x8*>(p);
}
__device__ __forceinline__ bf16x8 as_bf(u16x8 v){
  return __builtin_bit_cast(bf16x8, v);
}

// async global->LDS, 16B per lane; LDS dest = wave-uniform base + lane*16 (HW)
__device__ __forceinline__ void gload16(const void* g, void* l){
  __builtin_amdgcn_global_load_lds(
      (const __attribute__((address_space(1))) void*)g,
      (__attribute__((address_space(3))) void*)l, 16, 0, 0);
}

// ---------------- embed: x = bf16(wte[idx] + wpe[s]) ----------------
__global__ __launch_bounds__(256) void embed_kernel(
    const int* __restrict__ idx, const float* __restrict__ wte,
    const float* __restrict__ wpe, u16* __restrict__ x)
{
  int tok = blockIdx.x, tid = threadIdx.x;
  int id = idx[tok];
  int s = tok & (SEQ - 1);
  f32x4 a = *reinterpret_cast<const f32x4*>(&wte[(size_t)id * E + tid * 4]);
  f32x4 p = *reinterpret_cast<const f32x4*>(&wpe[(size_t)s * E + tid * 4]);
  u16x4 r;
  #pragma unroll
  for (int j = 0; j < 4; j++) r[j] = f2bf(a[j] + p[j]);
  *reinterpret_cast<u16x4*>(&x[(size_t)tok * E + tid * 4]) = r;
}

// ---------------- layernorm: h = LN(x)*w + b (bf16 x, bf16 out) ----------------
__global__ __launch_bounds__(256) void ln_kernel(
    const u16* __restrict__ x, const float* __restrict__ w,
    const float* __restrict__ b, u16* __restrict__ h)
{
  int row = blockIdx.x, tid = threadIdx.x;
  u16x4 xv = *reinterpret_cast<const u16x4*>(&x[(size_t)row * E + tid * 4]);
  f32x4 v;
  #pragma unroll
  for (int j = 0; j < 4; j++) v[j] = bf2f(xv[j]);
  float s = v[0] + v[1] + v[2] + v[3];
  float q = v[0]*v[0] + v[1]*v[1] + v[2]*v[2] + v[3]*v[3];
  #pragma unroll
  for (int mm = 1; mm < 64; mm <<= 1){
    s += __shfl_xor(s, mm);
    q += __shfl_xor(q, mm);
  }
  __shared__ float red[8];
  int wv = tid >> 6;
  if ((tid & 63) == 0){ red[wv] = s; red[4 + wv] = q; }
  __syncthreads();
  s = red[0] + red[1] + red[2] + red[3];
  q = red[4] + red[5] + red[6] + red[7];
  float mean = s * (1.0f / E);
  float var = q * (1.0f / E) - mean * mean;
  float rstd = rsqrtf(var + 1e-5f);
  f32x4 wv4 = *reinterpret_cast<const f32x4*>(w + tid * 4);
  f32x4 bv4 = *reinterpret_cast<const f32x4*>(b + tid * 4);
  u16x4 o;
  #pragma unroll
  for (int j = 0; j < 4; j++)
    o[j] = f2bf((v[j] - mean) * rstd * wv4[j] + bv4[j]);
  *reinterpret_cast<u16x4*>(&h[(size_t)row * E + tid * 4]) = o;
}

// ---- fused residual+LN: v = x + p (f32); x = bf16(v); h = LN(v)*w + b ----
__global__ __launch_bounds__(256) void lnadd_kernel(
    u16* __restrict__ x, const u16* __restrict__ p,
    const float* __restrict__ w, const float* __restrict__ b,
    u16* __restrict__ h)
{
  int row = blockIdx.x, tid = threadIdx.x;
  u16* xr = x + (size_t)row * E + tid * 4;
  u16x4 xv = *reinterpret_cast<const u16x4*>(xr);
  u16x4 pv = *reinterpret_cast<const u16x4*>(&p[(size_t)row * E + tid * 4]);
  f32x4 v;
  u16x4 nx;
  #pragma unroll
  for (int j = 0; j < 4; j++){
    v[j] = bf2f(xv[j]) + bf2f(pv[j]);
    nx[j] = f2bf(v[j]);
  }
  *reinterpret_cast<u16x4*>(xr) = nx;
  float s = v[0] + v[1] + v[2] + v[3];
  float q = v[0]*v[0] + v[1]*v[1] + v[2]*v[2] + v[3]*v[3];
  #pragma unroll
  for (int mm = 1; mm < 64; mm <<= 1){
    s += __shfl_xor(s, mm);
    q += __shfl_xor(q, mm);
  }
  __shared__ float red[8];
  int wv = tid >> 6;
  if ((tid & 63) == 0){ red[wv] = s; red[4 + wv] = q; }
  __syncthreads();
  s = red[0] + red[1] + red[2] + red[3];
  q = red[4] + red[5] + red[6] + red[7];
  float mean = s * (1.0f / E);
  float var = q * (1.0f / E) - mean * mean;
  float rstd = rsqrtf(var + 1e-5f);
  f32x4 wv4 = *reinterpret_cast<const f32x4*>(w + tid * 4);
  f32x4 bv4 = *reinterpret_cast<const f32x4*>(b + tid * 4);
  u16x4 o;
  #pragma unroll
  for (int j = 0; j < 4; j++)
    o[j] = f2bf((v[j] - mean) * rstd * wv4[j] + bv4[j]);
  *reinterpret_cast<u16x4*>(&h[(size_t)row * E + tid * 4]) = o;
}

// ------- merged per-layer weight convert+transpose (all Nsrc % 64 == 0) -------
__global__ __launch_bounds__(256) void wconv4_kernel(
    const float* __restrict__ qw, const float* __restrict__ ow,
    const float* __restrict__ f1, const float* __restrict__ f2,
    u16* __restrict__ dq, u16* __restrict__ d_unused, u16* __restrict__ d1,
    u16* __restrict__ d2, u16* __restrict__ dw_out)
{
  const int bid = blockIdx.x, tid = threadIdx.x;
  const float* W; u16* Wt; int K, Nsrc, nx, base;
  if (bid < 768)      { W = qw; Wt = dq;     K = 1024; Nsrc = 3072; nx = 48; base = 0; }
  else if (bid < 1024){ W = ow; Wt = dw_out; K = 1024; Nsrc = 1024; nx = 16; base = 768; }
  else if (bid < 2048){ W = f1; Wt = d1;     K = 1024; Nsrc = 4096; nx = 64; base = 1024; }
  else                { W = f2; Wt = d2;     K = 4096; Nsrc = 1024; nx = 16; base = 2048; }
  const int t = bid - base;
  const int n0 = (t % nx) * 64, k0 = (t / nx) * 64;

  __shared__ float T[64][65];
  const int c = (tid & 15) * 4, rbase = tid >> 4;
  #pragma unroll
  for (int p = 0; p < 4; p++){
    int r = rbase + p * 16;
    f32x4 v = *reinterpret_cast<const f32x4*>(&W[(size_t)(k0 + r) * Nsrc + n0 + c]);
    T[r][c] = v[0]; T[r][c+1] = v[1]; T[r][c+2] = v[2]; T[r][c+3] = v[3];
  }
  __syncthreads();
  const int nr = tid >> 2, ks = (tid & 3) * 16;
  u16x8 o0, o1;
  #pragma unroll
  for (int i = 0; i < 8; i++){
    o0[i] = f2bf(T[ks + i][nr]);
    o1[i] = f2bf(T[ks + 8 + i][nr]);
  }
  u16* dst = &Wt[(size_t)(n0 + nr) * K + k0 + ks];
  *reinterpret_cast<u16x8*>(dst) = o0;
  *reinterpret_cast<u16x8*>(dst + 8) = o1;
}

// ------- single weight convert+transpose (head: Nsrc=1000 padded to 1024) -----
__global__ __launch_bounds__(256) void wconv_kernel(
    const float* __restrict__ W, u16* __restrict__ Wt,
    int K, int Nsrc, int N)
{
  __shared__ float T[64][65];
  const int tid = threadIdx.x;
  const int n0 = blockIdx.x * 64, k0 = blockIdx.y * 64;
  const int c = (tid & 15) * 4, rbase = tid >> 4;
  #pragma unroll
  for (int p = 0; p < 4; p++){
    int r = rbase + p * 16;
    #pragma unroll
    for (int j = 0; j < 4; j++){
      int n = n0 + c + j;
      T[r][c + j] = (n < Nsrc) ? W[(size_t)(k0 + r) * Nsrc + n] : 0.0f;
    }
  }
  __syncthreads();
  const int nr = tid >> 2, ks = (tid & 3) * 16;
  u16x8 o0, o1;
  #pragma unroll
  for (int i = 0; i < 8; i++){
    o0[i] = f2bf(T[ks + i][nr]);
    o1[i] = f2bf(T[ks + 8 + i][nr]);
  }
  u16* dst = &Wt[(size_t)(n0 + nr) * K + k0 + ks];
  *reinterpret_cast<u16x8*>(dst) = o0;
  *reinterpret_cast<u16x8*>(dst + 8) = o1;
}

// ---------------- GEMM: C = A(bf16)[M,K] @ Wt(bf16)[N,K]^T + bias ----------------
// NS=4 ring, BK=32, phase split (r13):
//   [ds_read frags(c) -> counted VMCNT -> s_barrier -> setprio+MFMA(c) -> STAGE(c+3)]
// Uniform staging RPW in {3,4}; non-uniform (BM=256/BN=192): waves 0-3 stage 4 A,
// waves 4-7 stage 3 B; counted vmcnt uses the wave's own loads-per-chunk.
// T1 XCD swizzle, T2 16B-slot XOR swizzle, T5 setprio.
enum { EPI_BF16 = 0, EPI_GELU = 1, EPI_OUT = 3 };

template<int EPI, int NW, int NWX, int FM, int FN, int MINW>
__global__ __launch_bounds__(NW * 64, MINW) void gemm2_kernel(
    const u16* __restrict__ A, const u16* __restrict__ Wt,
    const float* __restrict__ bias, void* __restrict__ outp,
    int M, int N, int K)
{
  constexpr int BM = FM * 16 * (NW / NWX);
  constexpr int BN = FN * 16 * NWX;
  constexpr int SLOT = (BM + BN) * 32;       // u16 per slot (A | B), BK=32
  constexpr int GROUPS = (BM + BN) / 16;
  constexpr bool UNI = (GROUPS % NW) == 0;
  constexpr int RPW = UNI ? GROUPS / NW : 0; // uniform groups per wave
  constexpr int NS = 4;
  extern __shared__ u16 lds[];               // NS * SLOT * 2 bytes

  const int tid = threadIdx.x;
  const int lane = tid & 63, w = tid >> 6;
  const int l15 = lane & 15, g = lane >> 4;
  const int wr = w / NWX, wc = w % NWX;
  const int wrbase = wr * FM * 16, wcbase = wc * FN * 16;

  // T1: bijective XCD swizzle (all grids have nwg % 8 == 0)
  const int nwgx = gridDim.x;
  const int bid = blockIdx.y * nwgx + blockIdx.x;
  const int cpx = (nwgx * gridDim.y) >> 3;
  const int swz = (bid & 7) * cpx + (bid >> 3);
  const int bm = (swz / nwgx) * BM, bn = (swz % nwgx) * BN;

  const u16* Abase = A + (size_t)bm * K;
  const u16* Bbase = Wt + (size_t)bn * K;

  f32x4 acc[FM][FN];
  #pragma unroll
  for (int i = 0; i < FM; i++)
    #pragma unroll
    for (int j = 0; j < FN; j++)
      acc[i][j] = f32x4{0.f, 0.f, 0.f, 0.f};

  // stage chunk cc into slot s. LDS linear [row][32k]; source 16B-slot pre-swizzled.
  const int lr = lane >> 2, ps = lane & 3;
  const int ss = ps ^ ((lane >> 4) & 3);     // (row>>2)&3 == (lane>>4)&3 (base%16==0)
  auto STAGE = [&](int s, int cc){
    const int k0 = cc * 32;
    u16* As = lds + s * SLOT;
    u16* Bs = As + BM * 32;
    if constexpr (UNI){
      #pragma unroll
      for (int j = 0; j < RPW; j++){
        int base = (w * RPW + j) * 16;
        if (base < BM){
          gload16(&Abase[(size_t)(base + lr) * K + k0 + ss * 8], As + base * 32);
        } else {
          int rb = base - BM;
          gload16(&Bbase[(size_t)(rb + lr) * K + k0 + ss * 8], Bs + rb * 32);
        }
      }
    } else {
      // BM=256 (16 A-groups), BN=192 (12 B-groups): w<4 -> 4 A; w>=4 -> 3 B
      static_assert(BM == 256 && BN == 192, "non-uniform path is specialized");
      if (w < 4){
        #pragma unroll
        for (int j = 0; j < 4; j++){
          int base = (w * 4 + j) * 16;
          gload16(&Abase[(size_t)(base + lr) * K + k0 + ss * 8], As + base * 32);
        }
      } else {
        #pragma unroll
        for (int j = 0; j < 3; j++){
          int rb = ((w - 4) * 3 + j) * 16;
          gload16(&Bbase[(size_t)(rb + lr) * K + k0 + ss * 8], Bs + rb * 32);
        }
      }
    }
  };
  // counted wait: allow the newest chunk's loads (this wave's count) to stay in flight
  auto WAIT1 = [&](){
    if constexpr (UNI){
      static_assert(!UNI || RPW == 4 || RPW == 3, "vmcnt literal covers RPW 3/4");
      if constexpr (RPW == 4) { VMCNT(4); } else { VMCNT(3); }
    } else {
      if (w < 4) { VMCNT(4); } else { VMCNT(3); }
    }
  };

  const int nt = K >> 5;                     // >= 32 for all our shapes
  STAGE(0, 0); STAGE(1, 1); STAGE(2, 2);
  WAIT1();                                   // chunks 0,1 landed (chunk 2 in flight)
  __builtin_amdgcn_sched_barrier(0);
  __builtin_amdgcn_s_barrier();
  __builtin_amdgcn_sched_barrier(0);

  int sl = 0;
  for (int c = 0; c < nt; c++){
    // ---- ds_read frags of chunk c (visible since previous barrier) ----
    const u16* As = lds + sl * SLOT;
    const u16* Bs = As + BM * 32;
    bf16x8 af[FM], bf[FN];
    const int rsw = (g ^ (l15 >> 2)) * 8;    // swizzled 16B slot on read
    #pragma unroll
    for (int mf = 0; mf < FM; mf++)
      af[mf] = ld_bf8(&As[(wrbase + mf * 16 + l15) * 32 + rsw]);
    #pragma unroll
    for (int nf = 0; nf < FN; nf++)
      bf[nf] = ld_bf8(&Bs[(wcbase + nf * 16 + l15) * 32 + rsw]);
    __builtin_amdgcn_sched_barrier(0);
    // ---- counted vmcnt: chunk c+1 landed before the barrier releases ----
    if (c + 2 <= nt - 1) { WAIT1(); } else { VMCNT(0); }
    __builtin_amdgcn_sched_barrier(0);
    __builtin_amdgcn_s_barrier();            // chunk c+1 visible; reads of c issued
    __builtin_amdgcn_sched_barrier(0);
    // ---- MFMA ----
    __builtin_amdgcn_s_setprio(1);
    #pragma unroll
    for (int mf = 0; mf < FM; mf++)
      #pragma unroll
      for (int nf = 0; nf < FN; nf++)
        acc[mf][nf] = __builtin_amdgcn_mfma_f32_16x16x32_bf16(
            af[mf], bf[nf], acc[mf][nf], 0, 0, 0);
    __builtin_amdgcn_s_setprio(0);
    // ---- prefetch chunk c+3 into slot (c-1)%4 (dead once waves passed barrier(c)) ----
    if (c + 3 < nt){
      int s2 = sl + 3; if (s2 >= NS) s2 -= NS;
      STAGE(s2, c + 3);
    }
    sl++; if (sl >= NS) sl -= NS;
  }

  // epilogue (C/D: col = lane&15, row = (lane>>4)*4 + reg)
  #pragma unroll
  for (int mf = 0; mf < FM; mf++){
    #pragma unroll
    for (int nf = 0; nf < FN; nf++){
      int col = bn + wcbase + nf * 16 + l15;
      float bv = bias[col];
      #pragma unroll
      for (int r = 0; r < 4; r++){
        int row = bm + wrbase + mf * 16 + g * 4 + r;
        float v = acc[mf][nf][r] + bv;
        if constexpr (EPI == EPI_BF16){
          ((u16*)outp)[(size_t)row * N + col] = f2bf(v);
        } else if constexpr (EPI == EPI_GELU){
          ((u16*)outp)[(size_t)row * N + col] =
              f2bf(0.5f * v * (1.0f + erff(v * 0.70710678118654752f)));
        } else {
          if (col < VOC)
            ((float*)outp)[(size_t)row * VOC + col] = v;
        }
      }
    }
  }
}

// ---------------- flash attention (causal), dual paired 64-row q-blocks ----------------
// Grid (4, NH, NB): 512 thr (8 waves). Waves 0-3 own pair {pr, 15-pr}; waves 4-7
// own pair {7-pr, 8+pr}. Per-block MFMA work = 34 tile-computations for every pr
// (perfectly balanced); K/V staged once per block (58 tiles total vs 100 before).
// PV key axis permuted: c' = 4*(k&15)+(k>>4) on BOTH P and Vt columns.
__global__ __launch_bounds__(512) void attn_kernel(
    const u16* __restrict__ qkv, u16* __restrict__ y)
{
  __shared__ u16 Kl[64 * 64];       // [key][dslot swizzled], 8KB
  __shared__ u16 Vt[64 * 72];       // [d][c'], stride 72, 9KB
  __shared__ u16 Pl[8 * 16 * 72];   // per-wave [q][c'], 18KB
  const int pr = blockIdx.x, hh = blockIdx.y, b = blockIdx.z;
  const int tid = threadIdx.x;
  const int lane = tid & 63, w = tid >> 6;
  const int w4 = w & 3, wg = w >> 2;
  const int l15 = lane & 15, g = lane >> 4;
  const size_t tokbase = (size_t)b * SEQ;
  // wave-group pairs: wg0 -> {pr, 15-pr}; wg1 -> {7-pr, 8+pr}
  const int qs0 = (wg == 0 ? pr : 7 - pr) * 64;
  const int qs1 = (wg == 0 ? 15 - pr : 8 + pr) * 64;
  const int qstart[2] = { qs0, qs1 };

  int qbase[2], dt[2];
  u16x8 q0[2], q1[2];
  f32x4 o[2][4];
  float m[2][4], llp[2][4];
  #pragma unroll
  for (int st = 0; st < 2; st++){
    qbase[st] = qstart[st] + w4 * 16;
    dt[st] = qbase[st] >> 6;            // diagonal 64-key tile index
    const u16* qp = &qkv[(tokbase + qbase[st] + l15) * (3 * E) + hh * HD];
    u16x8 ra = *reinterpret_cast<const u16x8*>(&qp[g * 8]);
    u16x8 rb = *reinterpret_cast<const u16x8*>(&qp[32 + g * 8]);
    #pragma unroll
    for (int j = 0; j < 8; j++){
      q0[st][j] = f2bf(bf2f(ra[j]) * 0.125f);
      q1[st][j] = f2bf(bf2f(rb[j]) * 0.125f);
    }
    #pragma unroll
    for (int dc = 0; dc < 4; dc++) o[st][dc] = f32x4{0.f, 0.f, 0.f, 0.f};
    #pragma unroll
    for (int r = 0; r < 4; r++){ m[st][r] = -1e30f; llp[st][r] = 0.f; }
  }

  u16* Pw = &Pl[w * 16 * 72];
  const int T = 16 - pr;              // tiles to stage (covers all four members)

  for (int t = 0; t < T; t++){
    const int k0 = t * 64;
    __syncthreads();
    // ---- stage K (swizzled source -> linear LDS), 1 gload16/wave ----
    {
      int row = w * 8 + (lane >> 3);
      int sl = lane & 7;
      const u16* src = &qkv[(tokbase + k0 + row) * (3 * E) + E + hh * HD
                            + ((sl ^ (row & 7)) * 8)];
      gload16(src, &Kl[w * 512]);
    }
    // ---- stage V into permuted layout: Vt[d][c'] = V[k][d], c'=4*(k&15)+(k>>4) ----
    {
      int d0 = (tid & 15) * 4;
      int s  = (tid >> 4) & 15;
      int mh = tid >> 8;                    // 0,1
      int kA = s + 32 * mh;                 // c' = 4s+2mh
      const u16* vpA = &qkv[(tokbase + k0 + kA) * (3 * E) + 2 * E + hh * HD + d0];
      const u16* vpB = vpA + 16 * (3 * E);  // key kA+16 -> c' = 4s+2mh+1
      u16x4 va = *reinterpret_cast<const u16x4*>(vpA);
      u16x4 vb = *reinterpret_cast<const u16x4*>(vpB);
      #pragma unroll
      for (int i = 0; i < 4; i++)
        *reinterpret_cast<u32*>(&Vt[(d0 + i) * 72 + 4 * s + 2 * mh]) =
            (u32)va[i] | ((u32)vb[i] << 16);
    }
    __syncthreads();

    #pragma unroll
    for (int st = 0; st < 2; st++){
      if (t > dt[st]) continue;
      const bool diag = (t == dt[st]);
      f32x4 s[4];
      #pragma unroll
      for (int kg = 0; kg < 4; kg++){
        int key = kg * 16 + l15;
        const u16* kb = &Kl[key * 64];
        bf16x8 k0f = ld_bf8(&kb[(g ^ (key & 7)) * 8]);
        bf16x8 k1f = ld_bf8(&kb[((4 + g) ^ (key & 7)) * 8]);
        f32x4 z = f32x4{0.f, 0.f, 0.f, 0.f};
        z = __builtin_amdgcn_mfma_f32_16x16x32_bf16(as_bf(q0[st]), k0f, z, 0, 0, 0);
        z = __builtin_amdgcn_mfma_f32_16x16x32_bf16(as_bf(q1[st]), k1f, z, 0, 0, 0);
        s[kg] = z;
      }
      if (diag){
        #pragma unroll
        for (int kg = 0; kg < 4; kg++){
          int key = k0 + kg * 16 + l15;
          #pragma unroll
          for (int r = 0; r < 4; r++){
            int q = qbase[st] + g * 4 + r;
            s[kg][r] = (key <= q) ? s[kg][r] : -1e9f;
          }
        }
      }
      float lmax[4];
      bool need = false;
      #pragma unroll
      for (int r = 0; r < 4; r++){
        lmax[r] = fmaxf(fmaxf(s[0][r], s[1][r]), fmaxf(s[2][r], s[3][r]));
        need = need || (lmax[r] > m[st][r] + 8.0f);
      }
      if (__any(need)){
        #pragma unroll
        for (int r = 0; r < 4; r++){
          float x = lmax[r];
          x = fmaxf(x, __shfl_xor(x, 1));
          x = fmaxf(x, __shfl_xor(x, 2));
          x = fmaxf(x, __shfl_xor(x, 4));
          x = fmaxf(x, __shfl_xor(x, 8));
          float mn = fmaxf(m[st][r], x);
          float al = __expf(m[st][r] - mn);
          m[st][r] = mn;
          llp[st][r] *= al;
          #pragma unroll
          for (int dc = 0; dc < 4; dc++) o[st][dc][r] *= al;
        }
      }
      #pragma unroll
      for (int r = 0; r < 4; r++){
        float p0 = __expf(s[0][r] - m[st][r]);
        float p1 = __expf(s[1][r] - m[st][r]);
        float p2 = __expf(s[2][r] - m[st][r]);
        float p3 = __expf(s[3][r] - m[st][r]);
        llp[st][r] += (p0 + p1) + (p2 + p3);
        u16x4 pp = { f2bf(p0), f2bf(p1), f2bf(p2), f2bf(p3) };
        *reinterpret_cast<u16x4*>(&Pw[(g * 4 + r) * 72 + 4 * l15]) = pp;
      }
      bf16x8 pa0 = ld_bf8(&Pw[l15 * 72 + g * 8]);
      bf16x8 pa1 = ld_bf8(&Pw[l15 * 72 + 32 + g * 8]);
      #pragma unroll
      for (int dc = 0; dc < 4; dc++){
        bf16x8 v0 = ld_bf8(&Vt[(dc * 16 + l15) * 72 + g * 8]);
        bf16x8 v1 = ld_bf8(&Vt[(dc * 16 + l15) * 72 + 32 + g * 8]);
        o[st][dc] = __builtin_amdgcn_mfma_f32_16x16x32_bf16(pa0, v0, o[st][dc], 0, 0, 0);
        o[st][dc] = __builtin_amdgcn_mfma_f32_16x16x32_bf16(pa1, v1, o[st][dc], 0, 0, 0);
      }
    }
  }

  #pragma unroll
  for (int st = 0; st < 2; st++){
    #pragma unroll
    for (int r = 0; r < 4; r++){
      float rs = llp[st][r];
      rs += __shfl_xor(rs, 1);
      rs += __shfl_xor(rs, 2);
      rs += __shfl_xor(rs, 4);
      rs += __shfl_xor(rs, 8);
      float inv = 1.0f / rs;
      int row = qbase[st] + g * 4 + r;
      #pragma unroll
      for (int dc = 0; dc < 4; dc++){
        int col = hh * HD + dc * 16 + l15;
        y[(tokbase + row) * E + col] = f2bf(o[st][dc][r] * inv);
      }
    }
  }
}

// ---------------- head bias pad [1000] -> [1024] f32 ----------------
__global__ __launch_bounds__(256) void biaspad_kernel(
    const float* __restrict__ hb, float* __restrict__ bpad)
{
  int i = blockIdx.x * 256 + threadIdx.x;
  if (i < 1024) bpad[i] = (i < VOC) ? hb[i] : 0.0f;
}

// ---------------- launch ----------------
extern "C" void kernel_launch(void* const* d_in, const int* in_sizes, int n_in,
                              void* d_out, int out_size, void* d_ws, size_t ws_size,
                              hipStream_t stream)
{
  const int*   idx    = (const int*)  d_in[0];
  const float* wte    = (const float*)d_in[1];
  const float* wpe    = (const float*)d_in[2];
  const float* ln1_w  = (const float*)d_in[3];
  const float* ln1_b  = (const float*)d_in[4];
  const float* qkv_w  = (const float*)d_in[5];
  const float* qkv_b  = (const float*)d_in[6];
  const float* out_w  = (const float*)d_in[7];
  const float* out_b  = (const float*)d_in[8];
  const float* ln2_w  = (const float*)d_in[9];
  const float* ln2_b  = (const float*)d_in[10];
  const float* fc1_w  = (const float*)d_in[11];
  const float* fc1_b  = (const float*)d_in[12];
  const float* fc2_w  = (const float*)d_in[13];
  const float* fc2_b  = (const float*)d_in[14];
  const float* lnf_w  = (const float*)d_in[15];
  const float* lnf_b  = (const float*)d_in[16];
  const float* head_w = (const float*)d_in[17];
  const float* head_b = (const float*)d_in[18];

  char* ws = (char*)d_ws;
  u16*   x    = (u16*)  (ws + 0);            // 4096x1024 bf16   8388608
  u16*   h    = (u16*)  (ws + 8388608);      // 4096x1024 bf16   8388608
  u16*   qkvb = (u16*)  (ws + 16777216);     // 4096x3072 bf16  25165824
  u16*   y    = (u16*)  (ws + 41943040);     // 4096x1024 bf16   8388608
  u16*   g    = (u16*)  (ws + 50331648);     // 4096x4096 bf16  33554432
  u16*   wq   = (u16*)  (ws + 83886080);     // 3072x1024 bf16   6291456
  u16*   wo   = (u16*)  (ws + 90177536);     // 1024x1024 bf16   2097152
  u16*   w1   = (u16*)  (ws + 92274688);     // 4096x1024 bf16   8388608
  u16*   w2   = (u16*)  (ws + 100663296);    // 1024x4096 bf16   8388608
  u16*   wh   = (u16*)  (ws + 109051904);    // 1024x1024 bf16   2097152
  float* hbp  = (float*)(ws + 111149056);    // 1024 f32            4096
  u16*   p    = (u16*)  (ws + 111153152);    // 4096x1024 bf16   8388608
  // total: 119541760 bytes (~114 MiB)

  constexpr int LDS_QKV = 4 * (448 * 32) * 2;     // 114688 bytes (BM256/BN192)
  constexpr int LDS_BIG = 4 * (512 * 32) * 2;     // 131072 bytes (BM256/BN256)
  constexpr int LDS_SML = 4 * (192 * 32) * 2;     // 49152 bytes (BM128/BN64)
  hipFuncSetAttribute((const void*)gemm2_kernel<EPI_BF16, 8, 4, 8, 3, 2>,
                      hipFuncAttributeMaxDynamicSharedMemorySize, LDS_QKV);
  hipFuncSetAttribute((const void*)gemm2_kernel<EPI_GELU, 8, 4, 8, 4, 2>,
                      hipFuncAttributeMaxDynamicSharedMemorySize, LDS_BIG);
  hipFuncSetAttribute((const void*)gemm2_kernel<EPI_BF16, 4, 2, 4, 2, 2>,
                      hipFuncAttributeMaxDynamicSharedMemorySize, LDS_SML);
  hipFuncSetAttribute((const void*)gemm2_kernel<EPI_OUT, 4, 2, 4, 2, 2>,
                      hipFuncAttributeMaxDynamicSharedMemorySize, LDS_SML);

  embed_kernel<<<MTOK, 256, 0, stream>>>(idx, wte, wpe, x);
  biaspad_kernel<<<4, 256, 0, stream>>>(head_b, hbp);

  for (int l = 0; l < NL; l++){
    if (l == 0){
      ln_kernel<<<MTOK, 256, 0, stream>>>(x, ln1_w, ln1_b, h);
    } else {
      lnadd_kernel<<<MTOK, 256, 0, stream>>>(x, p, ln1_w + l * E, ln1_b + l * E, h);
    }
    wconv4_kernel<<<3072, 256, 0, stream>>>(
        qkv_w + (size_t)l * E * 3 * E, out_w + (size_t)l * E * E,
        fc1_w + (size_t)l * E * HID, fc2_w + (size_t)l * HID * E,
        wq, nullptr, w1, w2, wo);
    gemm2_kernel<EPI_BF16, 8, 4, 8, 3, 2><<<dim3(16, 16), 512, LDS_QKV, stream>>>(
        h, wq, qkv_b + (size_t)l * 3 * E, qkvb, MTOK, 3 * E, E);
    attn_kernel<<<dim3(4, NH, NB), 512, 0, stream>>>(qkvb, y);
    gemm2_kernel<EPI_BF16, 4, 2, 4, 2, 2><<<dim3(16, 32), 256, LDS_SML, stream>>>(
        y, wo, out_b + (size_t)l * E, p, MTOK, E, E);
    lnadd_kernel<<<MTOK, 256, 0, stream>>>(x, p, ln2_w + l * E, ln2_b + l * E, h);
    gemm2_kernel<EPI_GELU, 8, 4, 8, 4, 2><<<dim3(16, 16), 512, LDS_BIG, stream>>>(
        h, w1, fc1_b + (size_t)l * HID, g, MTOK, HID, E);
    gemm2_kernel<EPI_BF16, 4, 2, 4, 2, 2><<<dim3(16, 32), 256, LDS_SML, stream>>>(
        g, w2, fc2_b + (size_t)l * E, p, MTOK, E, HID);
  }
  lnadd_kernel<<<MTOK, 256, 0, stream>>>(x, p, lnf_w, lnf_b, h);
  wconv_kernel<<<dim3(16, 16), 256, 0, stream>>>(head_w, wh, E, VOC, E);
  gemm2_kernel<EPI_OUT, 4, 2, 4, 2, 2><<<dim3(16, 32), 256, LDS_SML, stream>>>(
      h, wh, hbp, (float*)d_out, MTOK, E, E);
}

// Round 20
// 1761.408 us; speedup vs baseline: 1.1289x; 1.0053x over previous
//
#include <hip/hip_runtime.h>
#include <math.h>

// GPT fwd: B=4, S=1024, L=8, H=16, E=1024, D=64, HID=4096, V=1000
// Workspace requirement: ~114 MB (see offsets below).

typedef unsigned short u16;
typedef unsigned int u32;
typedef __attribute__((ext_vector_type(4))) float f32x4;
typedef __attribute__((ext_vector_type(8))) __bf16 bf16x8;
typedef __attribute__((ext_vector_type(8))) u16 u16x8;
typedef __attribute__((ext_vector_type(4))) u16 u16x4;

#define E 1024
#define HID 4096
#define NH 16
#define HD 64
#define SEQ 1024
#define NB 4
#define NL 8
#define MTOK 4096
#define VOC 1000

#define VMCNT(n) asm volatile("s_waitcnt vmcnt(" #n ")" ::: "memory")
#define LGKMCNT0() asm volatile("s_waitcnt lgkmcnt(0)" ::: "memory")

__device__ __forceinline__ u16 f2bf(float f){
  u32 u = __float_as_uint(f);
  u32 r = (u + 0x7fffu + ((u >> 16) & 1u)) >> 16;
  return (u16)r;
}
__device__ __forceinline__ float bf2f(u16 b){
  return __uint_as_float((u32)b << 16);
}
__device__ __forceinline__ bf16x8 ld_bf8(const u16* p){
  return *reinterpret_cast<const bf16x8*>(p);
}
__device__ __forceinline__ bf16x8 as_bf(u16x8 v){
  return __builtin_bit_cast(bf16x8, v);
}

// async global->LDS, 16B per lane; LDS dest = wave-uniform base + lane*16 (HW)
__device__ __forceinline__ void gload16(const void* g, void* l){
  __builtin_amdgcn_global_load_lds(
      (const __attribute__((address_space(1))) void*)g,
      (__attribute__((address_space(3))) void*)l, 16, 0, 0);
}

// ---------------- embed: x = bf16(wte[idx] + wpe[s]) ----------------
__global__ __launch_bounds__(256) void embed_kernel(
    const int* __restrict__ idx, const float* __restrict__ wte,
    const float* __restrict__ wpe, u16* __restrict__ x)
{
  int tok = blockIdx.x, tid = threadIdx.x;
  int id = idx[tok];
  int s = tok & (SEQ - 1);
  f32x4 a = *reinterpret_cast<const f32x4*>(&wte[(size_t)id * E + tid * 4]);
  f32x4 p = *reinterpret_cast<const f32x4*>(&wpe[(size_t)s * E + tid * 4]);
  u16x4 r;
  #pragma unroll
  for (int j = 0; j < 4; j++) r[j] = f2bf(a[j] + p[j]);
  *reinterpret_cast<u16x4*>(&x[(size_t)tok * E + tid * 4]) = r;
}

// ---------------- layernorm: h = LN(x)*w + b (bf16 x, bf16 out) ----------------
__global__ __launch_bounds__(256) void ln_kernel(
    const u16* __restrict__ x, const float* __restrict__ w,
    const float* __restrict__ b, u16* __restrict__ h)
{
  int row = blockIdx.x, tid = threadIdx.x;
  u16x4 xv = *reinterpret_cast<const u16x4*>(&x[(size_t)row * E + tid * 4]);
  f32x4 v;
  #pragma unroll
  for (int j = 0; j < 4; j++) v[j] = bf2f(xv[j]);
  float s = v[0] + v[1] + v[2] + v[3];
  float q = v[0]*v[0] + v[1]*v[1] + v[2]*v[2] + v[3]*v[3];
  #pragma unroll
  for (int mm = 1; mm < 64; mm <<= 1){
    s += __shfl_xor(s, mm);
    q += __shfl_xor(q, mm);
  }
  __shared__ float red[8];
  int wv = tid >> 6;
  if ((tid & 63) == 0){ red[wv] = s; red[4 + wv] = q; }
  __syncthreads();
  s = red[0] + red[1] + red[2] + red[3];
  q = red[4] + red[5] + red[6] + red[7];
  float mean = s * (1.0f / E);
  float var = q * (1.0f / E) - mean * mean;
  float rstd = rsqrtf(var + 1e-5f);
  f32x4 wv4 = *reinterpret_cast<const f32x4*>(w + tid * 4);
  f32x4 bv4 = *reinterpret_cast<const f32x4*>(b + tid * 4);
  u16x4 o;
  #pragma unroll
  for (int j = 0; j < 4; j++)
    o[j] = f2bf((v[j] - mean) * rstd * wv4[j] + bv4[j]);
  *reinterpret_cast<u16x4*>(&h[(size_t)row * E + tid * 4]) = o;
}

// ---- fused residual+LN: v = x + p (f32); x = bf16(v); h = LN(v)*w + b ----
__global__ __launch_bounds__(256) void lnadd_kernel(
    u16* __restrict__ x, const u16* __restrict__ p,
    const float* __restrict__ w, const float* __restrict__ b,
    u16* __restrict__ h)
{
  int row = blockIdx.x, tid = threadIdx.x;
  u16* xr = x + (size_t)row * E + tid * 4;
  u16x4 xv = *reinterpret_cast<const u16x4*>(xr);
  u16x4 pv = *reinterpret_cast<const u16x4*>(&p[(size_t)row * E + tid * 4]);
  f32x4 v;
  u16x4 nx;
  #pragma unroll
  for (int j = 0; j < 4; j++){
    v[j] = bf2f(xv[j]) + bf2f(pv[j]);
    nx[j] = f2bf(v[j]);
  }
  *reinterpret_cast<u16x4*>(xr) = nx;
  float s = v[0] + v[1] + v[2] + v[3];
  float q = v[0]*v[0] + v[1]*v[1] + v[2]*v[2] + v[3]*v[3];
  #pragma unroll
  for (int mm = 1; mm < 64; mm <<= 1){
    s += __shfl_xor(s, mm);
    q += __shfl_xor(q, mm);
  }
  __shared__ float red[8];
  int wv = tid >> 6;
  if ((tid & 63) == 0){ red[wv] = s; red[4 + wv] = q; }
  __syncthreads();
  s = red[0] + red[1] + red[2] + red[3];
  q = red[4] + red[5] + red[6] + red[7];
  float mean = s * (1.0f / E);
  float var = q * (1.0f / E) - mean * mean;
  float rstd = rsqrtf(var + 1e-5f);
  f32x4 wv4 = *reinterpret_cast<const f32x4*>(w + tid * 4);
  f32x4 bv4 = *reinterpret_cast<const f32x4*>(b + tid * 4);
  u16x4 o;
  #pragma unroll
  for (int j = 0; j < 4; j++)
    o[j] = f2bf((v[j] - mean) * rstd * wv4[j] + bv4[j]);
  *reinterpret_cast<u16x4*>(&h[(size_t)row * E + tid * 4]) = o;
}

// ------- merged per-layer weight convert+transpose (all Nsrc % 64 == 0) -------
__global__ __launch_bounds__(256) void wconv4_kernel(
    const float* __restrict__ qw, const float* __restrict__ ow,
    const float* __restrict__ f1, const float* __restrict__ f2,
    u16* __restrict__ dq, u16* __restrict__ d_unused, u16* __restrict__ d1,
    u16* __restrict__ d2, u16* __restrict__ dw_out)
{
  const int bid = blockIdx.x, tid = threadIdx.x;
  const float* W; u16* Wt; int K, Nsrc, nx, base;
  if (bid < 768)      { W = qw; Wt = dq;     K = 1024; Nsrc = 3072; nx = 48; base = 0; }
  else if (bid < 1024){ W = ow; Wt = dw_out; K = 1024; Nsrc = 1024; nx = 16; base = 768; }
  else if (bid < 2048){ W = f1; Wt = d1;     K = 1024; Nsrc = 4096; nx = 64; base = 1024; }
  else                { W = f2; Wt = d2;     K = 4096; Nsrc = 1024; nx = 16; base = 2048; }
  const int t = bid - base;
  const int n0 = (t % nx) * 64, k0 = (t / nx) * 64;

  __shared__ float T[64][65];
  const int c = (tid & 15) * 4, rbase = tid >> 4;
  #pragma unroll
  for (int p = 0; p < 4; p++){
    int r = rbase + p * 16;
    f32x4 v = *reinterpret_cast<const f32x4*>(&W[(size_t)(k0 + r) * Nsrc + n0 + c]);
    T[r][c] = v[0]; T[r][c+1] = v[1]; T[r][c+2] = v[2]; T[r][c+3] = v[3];
  }
  __syncthreads();
  const int nr = tid >> 2, ks = (tid & 3) * 16;
  u16x8 o0, o1;
  #pragma unroll
  for (int i = 0; i < 8; i++){
    o0[i] = f2bf(T[ks + i][nr]);
    o1[i] = f2bf(T[ks + 8 + i][nr]);
  }
  u16* dst = &Wt[(size_t)(n0 + nr) * K + k0 + ks];
  *reinterpret_cast<u16x8*>(dst) = o0;
  *reinterpret_cast<u16x8*>(dst + 8) = o1;
}

// ------- single weight convert+transpose (head: Nsrc=1000 padded to 1024) -----
__global__ __launch_bounds__(256) void wconv_kernel(
    const float* __restrict__ W, u16* __restrict__ Wt,
    int K, int Nsrc, int N)
{
  __shared__ float T[64][65];
  const int tid = threadIdx.x;
  const int n0 = blockIdx.x * 64, k0 = blockIdx.y * 64;
  const int c = (tid & 15) * 4, rbase = tid >> 4;
  #pragma unroll
  for (int p = 0; p < 4; p++){
    int r = rbase + p * 16;
    #pragma unroll
    for (int j = 0; j < 4; j++){
      int n = n0 + c + j;
      T[r][c + j] = (n < Nsrc) ? W[(size_t)(k0 + r) * Nsrc + n] : 0.0f;
    }
  }
  __syncthreads();
  const int nr = tid >> 2, ks = (tid & 3) * 16;
  u16x8 o0, o1;
  #pragma unroll
  for (int i = 0; i < 8; i++){
    o0[i] = f2bf(T[ks + i][nr]);
    o1[i] = f2bf(T[ks + 8 + i][nr]);
  }
  u16* dst = &Wt[(size_t)(n0 + nr) * K + k0 + ks];
  *reinterpret_cast<u16x8*>(dst) = o0;
  *reinterpret_cast<u16x8*>(dst + 8) = o1;
}

// ---------------- GEMM: C = A(bf16)[M,K] @ Wt(bf16)[N,K]^T + bias ----------------
// NS=4 ring, BK=32, phase split (r13):
//   [ds_read frags(c) -> counted VMCNT -> s_barrier -> setprio+MFMA(c) -> STAGE(c+3)]
// Uniform staging RPW in {3,4}; non-uniform (BM=256/BN=192): waves 0-3 stage 4 A,
// waves 4-7 stage 3 B; counted vmcnt uses the wave's own loads-per-chunk.
// T1 XCD swizzle, T2 16B-slot XOR swizzle, T5 setprio.
enum { EPI_BF16 = 0, EPI_GELU = 1, EPI_OUT = 3 };

template<int EPI, int NW, int NWX, int FM, int FN, int MINW>
__global__ __launch_bounds__(NW * 64, MINW) void gemm2_kernel(
    const u16* __restrict__ A, const u16* __restrict__ Wt,
    const float* __restrict__ bias, void* __restrict__ outp,
    int M, int N, int K)
{
  constexpr int BM = FM * 16 * (NW / NWX);
  constexpr int BN = FN * 16 * NWX;
  constexpr int SLOT = (BM + BN) * 32;       // u16 per slot (A | B), BK=32
  constexpr int GROUPS = (BM + BN) / 16;
  constexpr bool UNI = (GROUPS % NW) == 0;
  constexpr int RPW = UNI ? GROUPS / NW : 0; // uniform groups per wave
  constexpr int NS = 4;
  extern __shared__ u16 lds[];               // NS * SLOT * 2 bytes

  const int tid = threadIdx.x;
  const int lane = tid & 63, w = tid >> 6;
  const int l15 = lane & 15, g = lane >> 4;
  const int wr = w / NWX, wc = w % NWX;
  const int wrbase = wr * FM * 16, wcbase = wc * FN * 16;

  // T1: bijective XCD swizzle (all grids have nwg % 8 == 0)
  const int nwgx = gridDim.x;
  const int bid = blockIdx.y * nwgx + blockIdx.x;
  const int cpx = (nwgx * gridDim.y) >> 3;
  const int swz = (bid & 7) * cpx + (bid >> 3);
  const int bm = (swz / nwgx) * BM, bn = (swz % nwgx) * BN;

  const u16* Abase = A + (size_t)bm * K;
  const u16* Bbase = Wt + (size_t)bn * K;

  f32x4 acc[FM][FN];
  #pragma unroll
  for (int i = 0; i < FM; i++)
    #pragma unroll
    for (int j = 0; j < FN; j++)
      acc[i][j] = f32x4{0.f, 0.f, 0.f, 0.f};

  // stage chunk cc into slot s. LDS linear [row][32k]; source 16B-slot pre-swizzled.
  const int lr = lane >> 2, ps = lane & 3;
  const int ss = ps ^ ((lane >> 4) & 3);     // (row>>2)&3 == (lane>>4)&3 (base%16==0)
  auto STAGE = [&](int s, int cc){
    const int k0 = cc * 32;
    u16* As = lds + s * SLOT;
    u16* Bs = As + BM * 32;
    if constexpr (UNI){
      #pragma unroll
      for (int j = 0; j < RPW; j++){
        int base = (w * RPW + j) * 16;
        if (base < BM){
          gload16(&Abase[(size_t)(base + lr) * K + k0 + ss * 8], As + base * 32);
        } else {
          int rb = base - BM;
          gload16(&Bbase[(size_t)(rb + lr) * K + k0 + ss * 8], Bs + rb * 32);
        }
      }
    } else {
      // BM=256 (16 A-groups), BN=192 (12 B-groups): w<4 -> 4 A; w>=4 -> 3 B
      static_assert(BM == 256 && BN == 192, "non-uniform path is specialized");
      if (w < 4){
        #pragma unroll
        for (int j = 0; j < 4; j++){
          int base = (w * 4 + j) * 16;
          gload16(&Abase[(size_t)(base + lr) * K + k0 + ss * 8], As + base * 32);
        }
      } else {
        #pragma unroll
        for (int j = 0; j < 3; j++){
          int rb = ((w - 4) * 3 + j) * 16;
          gload16(&Bbase[(size_t)(rb + lr) * K + k0 + ss * 8], Bs + rb * 32);
        }
      }
    }
  };
  // counted wait: allow the newest chunk's loads (this wave's count) to stay in flight
  auto WAIT1 = [&](){
    if constexpr (UNI){
      static_assert(!UNI || RPW == 4 || RPW == 3, "vmcnt literal covers RPW 3/4");
      if constexpr (RPW == 4) { VMCNT(4); } else { VMCNT(3); }
    } else {
      if (w < 4) { VMCNT(4); } else { VMCNT(3); }
    }
  };

  const int nt = K >> 5;                     // >= 32 for all our shapes
  STAGE(0, 0); STAGE(1, 1); STAGE(2, 2);
  WAIT1();                                   // chunks 0,1 landed (chunk 2 in flight)
  __builtin_amdgcn_sched_barrier(0);
  __builtin_amdgcn_s_barrier();
  __builtin_amdgcn_sched_barrier(0);

  int sl = 0;
  for (int c = 0; c < nt; c++){
    // ---- ds_read frags of chunk c (visible since previous barrier) ----
    const u16* As = lds + sl * SLOT;
    const u16* Bs = As + BM * 32;
    bf16x8 af[FM], bf[FN];
    const int rsw = (g ^ (l15 >> 2)) * 8;    // swizzled 16B slot on read
    #pragma unroll
    for (int mf = 0; mf < FM; mf++)
      af[mf] = ld_bf8(&As[(wrbase + mf * 16 + l15) * 32 + rsw]);
    #pragma unroll
    for (int nf = 0; nf < FN; nf++)
      bf[nf] = ld_bf8(&Bs[(wcbase + nf * 16 + l15) * 32 + rsw]);
    __builtin_amdgcn_sched_barrier(0);
    // ---- counted vmcnt: chunk c+1 landed before the barrier releases ----
    if (c + 2 <= nt - 1) { WAIT1(); } else { VMCNT(0); }
    __builtin_amdgcn_sched_barrier(0);
    __builtin_amdgcn_s_barrier();            // chunk c+1 visible; reads of c issued
    __builtin_amdgcn_sched_barrier(0);
    // ---- MFMA ----
    __builtin_amdgcn_s_setprio(1);
    #pragma unroll
    for (int mf = 0; mf < FM; mf++)
      #pragma unroll
      for (int nf = 0; nf < FN; nf++)
        acc[mf][nf] = __builtin_amdgcn_mfma_f32_16x16x32_bf16(
            af[mf], bf[nf], acc[mf][nf], 0, 0, 0);
    __builtin_amdgcn_s_setprio(0);
    // ---- prefetch chunk c+3 into slot (c-1)%4 (dead once waves passed barrier(c)) ----
    if (c + 3 < nt){
      int s2 = sl + 3; if (s2 >= NS) s2 -= NS;
      STAGE(s2, c + 3);
    }
    sl++; if (sl >= NS) sl -= NS;
  }

  // epilogue (C/D: col = lane&15, row = (lane>>4)*4 + reg)
  #pragma unroll
  for (int mf = 0; mf < FM; mf++){
    #pragma unroll
    for (int nf = 0; nf < FN; nf++){
      int col = bn + wcbase + nf * 16 + l15;
      float bv = bias[col];
      #pragma unroll
      for (int r = 0; r < 4; r++){
        int row = bm + wrbase + mf * 16 + g * 4 + r;
        float v = acc[mf][nf][r] + bv;
        if constexpr (EPI == EPI_BF16){
          ((u16*)outp)[(size_t)row * N + col] = f2bf(v);
        } else if constexpr (EPI == EPI_GELU){
          ((u16*)outp)[(size_t)row * N + col] =
              f2bf(0.5f * v * (1.0f + erff(v * 0.70710678118654752f)));
        } else {
          if (col < VOC)
            ((float*)outp)[(size_t)row * VOC + col] = v;
        }
      }
    }
  }
}

// ---------------- flash attention (causal), dual paired 64-row q-blocks ----------------
// Grid (4, NH, NB): 512 thr (8 waves). Waves 0-3 own pair {pr, 15-pr}; waves 4-7
// own pair {7-pr, 8+pr}; balanced 34 tile-computations per block.
// K/V DOUBLE-BUFFERED with async-STAGE split (T14): issue K(t+1) gload + V(t+1)
// reg-loads BEFORE compute(t); after compute VMCNT(0) -> ds_write V(t+1) ->
// lgkmcnt(0) -> one s_barrier per tile. Buffer buf^1 written at iter t was last
// read in compute(t-1), whose ds_reads were consumed before the end-of-(t-1)
// barrier -> dependency-ordered, race-free.
// PV key axis permuted: c' = 4*(k&15)+(k>>4) on BOTH P and Vt columns.
__global__ __launch_bounds__(512) void attn_kernel(
    const u16* __restrict__ qkv, u16* __restrict__ y)
{
  __shared__ u16 Kl[2][64 * 64];    // [buf][key][dslot swizzled], 16KB
  __shared__ u16 Vt[2][64 * 72];    // [buf][d][c'], stride 72, 18KB
  __shared__ u16 Pl[8 * 16 * 72];   // per-wave [q][c'], 18KB
  const int pr = blockIdx.x, hh = blockIdx.y, b = blockIdx.z;
  const int tid = threadIdx.x;
  const int lane = tid & 63, w = tid >> 6;
  const int w4 = w & 3, wg = w >> 2;
  const int l15 = lane & 15, g = lane >> 4;
  const size_t tokbase = (size_t)b * SEQ;
  const int qs0 = (wg == 0 ? pr : 7 - pr) * 64;
  const int qs1 = (wg == 0 ? 15 - pr : 8 + pr) * 64;
  const int qstart[2] = { qs0, qs1 };

  // staging coordinates (constant per thread)
  const int krow = w * 8 + (lane >> 3);
  const int kslot = ((lane & 7) ^ (krow & 7)) * 8;
  const int vd0 = (tid & 15) * 4;
  const int vs  = (tid >> 4) & 15;
  const int vmh = tid >> 8;                 // 0,1
  const int vcpos = 4 * vs + 2 * vmh;
  const int vkA = vs + 32 * vmh;

  int qbase[2], dt[2];
  u16x8 q0[2], q1[2];
  f32x4 o[2][4];
  float m[2][4], llp[2][4];
  #pragma unroll
  for (int st = 0; st < 2; st++){
    qbase[st] = qstart[st] + w4 * 16;
    dt[st] = qbase[st] >> 6;
    const u16* qp = &qkv[(tokbase + qbase[st] + l15) * (3 * E) + hh * HD];
    u16x8 ra = *reinterpret_cast<const u16x8*>(&qp[g * 8]);
    u16x8 rb = *reinterpret_cast<const u16x8*>(&qp[32 + g * 8]);
    #pragma unroll
    for (int j = 0; j < 8; j++){
      q0[st][j] = f2bf(bf2f(ra[j]) * 0.125f);
      q1[st][j] = f2bf(bf2f(rb[j]) * 0.125f);
    }
    #pragma unroll
    for (int dc = 0; dc < 4; dc++) o[st][dc] = f32x4{0.f, 0.f, 0.f, 0.f};
    #pragma unroll
    for (int r = 0; r < 4; r++){ m[st][r] = -1e30f; llp[st][r] = 0.f; }
  }

  u16* Pw = &Pl[w * 16 * 72];
  const int T = 16 - pr;              // tiles (covers all four pair-members)

  // ---- prologue: stage tile 0 into buf 0 ----
  {
    gload16(&qkv[(tokbase + krow) * (3 * E) + E + hh * HD + kslot], &Kl[0][w * 512]);
    const u16* vpA = &qkv[(tokbase + vkA) * (3 * E) + 2 * E + hh * HD + vd0];
    u16x4 va = *reinterpret_cast<const u16x4*>(vpA);
    u16x4 vb = *reinterpret_cast<const u16x4*>(vpA + 16 * (3 * E));
    VMCNT(0);
    #pragma unroll
    for (int i = 0; i < 4; i++)
      *reinterpret_cast<u32*>(&Vt[0][(vd0 + i) * 72 + vcpos]) =
          (u32)va[i] | ((u32)vb[i] << 16);
  }
  __syncthreads();

  int buf = 0;
  for (int t = 0; t < T; t++){
    const int k0 = t * 64;
    const bool more = (t + 1 < T);
    u16x4 va, vb;
    // ---- issue next tile's loads (fly under compute) ----
    if (more){
      const int k0n = k0 + 64;
      gload16(&qkv[(tokbase + k0n + krow) * (3 * E) + E + hh * HD + kslot],
              &Kl[buf ^ 1][w * 512]);
      const u16* vpA = &qkv[(tokbase + k0n + vkA) * (3 * E) + 2 * E + hh * HD + vd0];
      va = *reinterpret_cast<const u16x4*>(vpA);
      vb = *reinterpret_cast<const u16x4*>(vpA + 16 * (3 * E));
    }

    // ---- compute tile t from buf ----
    #pragma unroll
    for (int st = 0; st < 2; st++){
      if (t > dt[st]) continue;
      const bool diag = (t == dt[st]);
      f32x4 s[4];
      #pragma unroll
      for (int kg = 0; kg < 4; kg++){
        int key = kg * 16 + l15;
        const u16* kb = &Kl[buf][key * 64];
        bf16x8 k0f = ld_bf8(&kb[(g ^ (key & 7)) * 8]);
        bf16x8 k1f = ld_bf8(&kb[((4 + g) ^ (key & 7)) * 8]);
        f32x4 z = f32x4{0.f, 0.f, 0.f, 0.f};
        z = __builtin_amdgcn_mfma_f32_16x16x32_bf16(as_bf(q0[st]), k0f, z, 0, 0, 0);
        z = __builtin_amdgcn_mfma_f32_16x16x32_bf16(as_bf(q1[st]), k1f, z, 0, 0, 0);
        s[kg] = z;
      }
      if (diag){
        #pragma unroll
        for (int kg = 0; kg < 4; kg++){
          int key = k0 + kg * 16 + l15;
          #pragma unroll
          for (int r = 0; r < 4; r++){
            int q = qbase[st] + g * 4 + r;
            s[kg][r] = (key <= q) ? s[kg][r] : -1e9f;
          }
        }
      }
      float lmax[4];
      bool need = false;
      #pragma unroll
      for (int r = 0; r < 4; r++){
        lmax[r] = fmaxf(fmaxf(s[0][r], s[1][r]), fmaxf(s[2][r], s[3][r]));
        need = need || (lmax[r] > m[st][r] + 8.0f);
      }
      if (__any(need)){
        #pragma unroll
        for (int r = 0; r < 4; r++){
          float xx = lmax[r];
          xx = fmaxf(xx, __shfl_xor(xx, 1));
          xx = fmaxf(xx, __shfl_xor(xx, 2));
          xx = fmaxf(xx, __shfl_xor(xx, 4));
          xx = fmaxf(xx, __shfl_xor(xx, 8));
          float mn = fmaxf(m[st][r], xx);
          float al = __expf(m[st][r] - mn);
          m[st][r] = mn;
          llp[st][r] *= al;
          #pragma unroll
          for (int dc = 0; dc < 4; dc++) o[st][dc][r] *= al;
        }
      }
      #pragma unroll
      for (int r = 0; r < 4; r++){
        float p0 = __expf(s[0][r] - m[st][r]);
        float p1 = __expf(s[1][r] - m[st][r]);
        float p2 = __expf(s[2][r] - m[st][r]);
        float p3 = __expf(s[3][r] - m[st][r]);
        llp[st][r] += (p0 + p1) + (p2 + p3);
        u16x4 pp = { f2bf(p0), f2bf(p1), f2bf(p2), f2bf(p3) };
        *reinterpret_cast<u16x4*>(&Pw[(g * 4 + r) * 72 + 4 * l15]) = pp;
      }
      bf16x8 pa0 = ld_bf8(&Pw[l15 * 72 + g * 8]);
      bf16x8 pa1 = ld_bf8(&Pw[l15 * 72 + 32 + g * 8]);
      #pragma unroll
      for (int dc = 0; dc < 4; dc++){
        bf16x8 v0 = ld_bf8(&Vt[buf][(dc * 16 + l15) * 72 + g * 8]);
        bf16x8 v1 = ld_bf8(&Vt[buf][(dc * 16 + l15) * 72 + 32 + g * 8]);
        o[st][dc] = __builtin_amdgcn_mfma_f32_16x16x32_bf16(pa0, v0, o[st][dc], 0, 0, 0);
        o[st][dc] = __builtin_amdgcn_mfma_f32_16x16x32_bf16(pa1, v1, o[st][dc], 0, 0, 0);
      }
    }

    // ---- land next tile: drain loads, write V, one barrier ----
    if (more){
      VMCNT(0);                              // K gload landed; V regs ready
      #pragma unroll
      for (int i = 0; i < 4; i++)
        *reinterpret_cast<u32*>(&Vt[buf ^ 1][(vd0 + i) * 72 + vcpos]) =
            (u32)va[i] | ((u32)vb[i] << 16);
    }
    LGKMCNT0();
    __builtin_amdgcn_sched_barrier(0);
    __builtin_amdgcn_s_barrier();
    __builtin_amdgcn_sched_barrier(0);
    buf ^= 1;
  }

  #pragma unroll
  for (int st = 0; st < 2; st++){
    #pragma unroll
    for (int r = 0; r < 4; r++){
      float rs = llp[st][r];
      rs += __shfl_xor(rs, 1);
      rs += __shfl_xor(rs, 2);
      rs += __shfl_xor(rs, 4);
      rs += __shfl_xor(rs, 8);
      float inv = 1.0f / rs;
      int row = qbase[st] + g * 4 + r;
      #pragma unroll
      for (int dc = 0; dc < 4; dc++){
        int col = hh * HD + dc * 16 + l15;
        y[(tokbase + row) * E + col] = f2bf(o[st][dc][r] * inv);
      }
    }
  }
}

// ---------------- head bias pad [1000] -> [1024] f32 ----------------
__global__ __launch_bounds__(256) void biaspad_kernel(
    const float* __restrict__ hb, float* __restrict__ bpad)
{
  int i = blockIdx.x * 256 + threadIdx.x;
  if (i < 1024) bpad[i] = (i < VOC) ? hb[i] : 0.0f;
}

// ---------------- launch ----------------
extern "C" void kernel_launch(void* const* d_in, const int* in_sizes, int n_in,
                              void* d_out, int out_size, void* d_ws, size_t ws_size,
                              hipStream_t stream)
{
  const int*   idx    = (const int*)  d_in[0];
  const float* wte    = (const float*)d_in[1];
  const float* wpe    = (const float*)d_in[2];
  const float* ln1_w  = (const float*)d_in[3];
  const float* ln1_b  = (const float*)d_in[4];
  const float* qkv_w  = (const float*)d_in[5];
  const float* qkv_b  = (const float*)d_in[6];
  const float* out_w  = (const float*)d_in[7];
  const float* out_b  = (const float*)d_in[8];
  const float* ln2_w  = (const float*)d_in[9];
  const float* ln2_b  = (const float*)d_in[10];
  const float* fc1_w  = (const float*)d_in[11];
  const float* fc1_b  = (const float*)d_in[12];
  const float* fc2_w  = (const float*)d_in[13];
  const float* fc2_b  = (const float*)d_in[14];
  const float* lnf_w  = (const float*)d_in[15];
  const float* lnf_b  = (const float*)d_in[16];
  const float* head_w = (const float*)d_in[17];
  const float* head_b = (const float*)d_in[18];

  char* ws = (char*)d_ws;
  u16*   x    = (u16*)  (ws + 0);            // 4096x1024 bf16   8388608
  u16*   h    = (u16*)  (ws + 8388608);      // 4096x1024 bf16   8388608
  u16*   qkvb = (u16*)  (ws + 16777216);     // 4096x3072 bf16  25165824
  u16*   y    = (u16*)  (ws + 41943040);     // 4096x1024 bf16   8388608
  u16*   g    = (u16*)  (ws + 50331648);     // 4096x4096 bf16  33554432
  u16*   wq   = (u16*)  (ws + 83886080);     // 3072x1024 bf16   6291456
  u16*   wo   = (u16*)  (ws + 90177536);     // 1024x1024 bf16   2097152
  u16*   w1   = (u16*)  (ws + 92274688);     // 4096x1024 bf16   8388608
  u16*   w2   = (u16*)  (ws + 100663296);    // 1024x4096 bf16   8388608
  u16*   wh   = (u16*)  (ws + 109051904);    // 1024x1024 bf16   2097152
  float* hbp  = (float*)(ws + 111149056);    // 1024 f32            4096
  u16*   p    = (u16*)  (ws + 111153152);    // 4096x1024 bf16   8388608
  // total: 119541760 bytes (~114 MiB)

  constexpr int LDS_QKV = 4 * (448 * 32) * 2;     // 114688 bytes (BM256/BN192)
  constexpr int LDS_BIG = 4 * (512 * 32) * 2;     // 131072 bytes (BM256/BN256)
  constexpr int LDS_SML = 4 * (192 * 32) * 2;     // 49152 bytes (BM128/BN64)
  hipFuncSetAttribute((const void*)gemm2_kernel<EPI_BF16, 8, 4, 8, 3, 2>,
                      hipFuncAttributeMaxDynamicSharedMemorySize, LDS_QKV);
  hipFuncSetAttribute((const void*)gemm2_kernel<EPI_GELU, 8, 4, 8, 4, 2>,
                      hipFuncAttributeMaxDynamicSharedMemorySize, LDS_BIG);
  hipFuncSetAttribute((const void*)gemm2_kernel<EPI_BF16, 4, 2, 4, 2, 2>,
                      hipFuncAttributeMaxDynamicSharedMemorySize, LDS_SML);
  hipFuncSetAttribute((const void*)gemm2_kernel<EPI_OUT, 4, 2, 4, 2, 2>,
                      hipFuncAttributeMaxDynamicSharedMemorySize, LDS_SML);

  embed_kernel<<<MTOK, 256, 0, stream>>>(idx, wte, wpe, x);
  biaspad_kernel<<<4, 256, 0, stream>>>(head_b, hbp);

  for (int l = 0; l < NL; l++){
    if (l == 0){
      ln_kernel<<<MTOK, 256, 0, stream>>>(x, ln1_w, ln1_b, h);
    } else {
      lnadd_kernel<<<MTOK, 256, 0, stream>>>(x, p, ln1_w + l * E, ln1_b + l * E, h);
    }
    wconv4_kernel<<<3072, 256, 0, stream>>>(
        qkv_w + (size_t)l * E * 3 * E, out_w + (size_t)l * E * E,
        fc1_w + (size_t)l * E * HID, fc2_w + (size_t)l * HID * E,
        wq, nullptr, w1, w2, wo);
    gemm2_kernel<EPI_BF16, 8, 4, 8, 3, 2><<<dim3(16, 16), 512, LDS_QKV, stream>>>(
        h, wq, qkv_b + (size_t)l * 3 * E, qkvb, MTOK, 3 * E, E);
    attn_kernel<<<dim3(4, NH, NB), 512, 0, stream>>>(qkvb, y);
    gemm2_kernel<EPI_BF16, 4, 2, 4, 2, 2><<<dim3(16, 32), 256, LDS_SML, stream>>>(
        y, wo, out_b + (size_t)l * E, p, MTOK, E, E);
    lnadd_kernel<<<MTOK, 256, 0, stream>>>(x, p, ln2_w + l * E, ln2_b + l * E, h);
    gemm2_kernel<EPI_GELU, 8, 4, 8, 4, 2><<<dim3(16, 16), 512, LDS_BIG, stream>>>(
        h, w1, fc1_b + (size_t)l * HID, g, MTOK, HID, E);
    gemm2_kernel<EPI_BF16, 4, 2, 4, 2, 2><<<dim3(16, 32), 256, LDS_SML, stream>>>(
        g, w2, fc2_b + (size_t)l * E, p, MTOK, E, HID);
  }
  lnadd_kernel<<<MTOK, 256, 0, stream>>>(x, p, lnf_w, lnf_b, h);
  wconv_kernel<<<dim3(16, 16), 256, 0, stream>>>(head_w, wh, E, VOC, E);
  gemm2_kernel<EPI_OUT, 4, 2, 4, 2, 2><<<dim3(16, 32), 256, LDS_SML, stream>>>(
      h, wh, hbp, (float*)d_out, MTOK, E, E);
}